// Round 1
// baseline (2330.768 us; speedup 1.0000x reference)
//
#include <hip/hip_runtime.h>

typedef unsigned int u32;

// problem dims
#define NTOP 50
#define NT_T 50
#define NRHO 300
#define NVOC 20000
#define NTH 800
#define NEH 200
#define NSRC 10
#define NBAT 256

// ws offsets (float units)
#define OFF_SCAL     0          // [0]=sum bows*log(s), [1]=kl_alpha, [2]=kl_eta, [3]=kl_theta_raw, [4]=pred_raw
#define OFF_MAPPED   16         // 500*200
#define OFF_HPRE     100016     // 256*800
#define OFF_DOCCNT   304816     // 50 ints
#define OFF_DOCLIST  304866     // 50*256 ints
#define OFF_XW       317700     // 500*800  [s][t][j]
#define OFF_ALPHAST  717700     // 2500*300 [(t*50+k)][r]
#define OFF_BIASHH   1467700    // 800
#define OFF_ETAS     1468500    // 10*50*50 [s][t][k]
#define OFF_WCOEF    1493500    // 256*50
#define OFF_MZ       1506300    // 2500*2 (m, Z)
#define OFF_H1       1511300    // 256*800
#define OFF_H2       1716100    // 256*800
#define OFF_WHH_H    1933700    // 80000 u32 (f16 pairs) [j][100]
#define OFF_ETAWH    2013700    // 12500 u32 [q][125]  q<50: mu_eta_W row, q>=50: ls_eta_W row
#define OFF_LOGITH   2026240    // 2500*20000 _Float16
#define MEMSET_BYTES ((size_t)OFF_XW * 4)
// total ws need: (2026240 + 25000000)*4 = 108,104,960 bytes

typedef _Float16 h2v __attribute__((ext_vector_type(2)));

__device__ inline float dot2u(u32 a, u32 b, float c){
  h2v ha = __builtin_bit_cast(h2v, a), hb = __builtin_bit_cast(h2v, b);
#if __has_builtin(__builtin_amdgcn_fdot2)
  return __builtin_amdgcn_fdot2(ha, hb, c, false);
#else
  return c + (float)ha.x*(float)hb.x + (float)ha.y*(float)hb.y;
#endif
}

__device__ inline u32 packh2(float lo, float hi){
  h2v h; h.x = (_Float16)lo; h.y = (_Float16)hi;
  return __builtin_bit_cast(u32, h);
}

__device__ inline void blockReduceAdd(float v, float* red, float* target){
  int tid = threadIdx.x;
  red[tid] = v; __syncthreads();
  for (int o = blockDim.x >> 1; o > 0; o >>= 1){
    if (tid < o) red[tid] += red[tid + o];
    __syncthreads();
  }
  if (tid == 0) atomicAdd(target, red[0]);
}

// ---------------- prep: row-permute alphas, f16-pack Whh & eta weights, bias merge, doc buckets --------
__global__ __launch_bounds__(256) void k_prep(
    const float* __restrict__ muq, const float* __restrict__ whh,
    const float* __restrict__ muEW, const float* __restrict__ lsEW,
    const float* __restrict__ bih, const float* __restrict__ bhh,
    const int* __restrict__ times, float* __restrict__ W)
{
  int idx = blockIdx.x*256 + threadIdx.x;
  float* alphasT = W + OFF_ALPHAST;
  u32* whhH = (u32*)(W + OFF_WHH_H);
  u32* etaWH = (u32*)(W + OFF_ETAWH);
  float* biasHH = W + OFF_BIASHH;
  int* docCnt = (int*)(W + OFF_DOCCNT);
  int* docList = (int*)(W + OFF_DOCLIST);
  if (idx < 750000){
    int k = idx / 15000; int rem = idx - k*15000; int t = rem/300; int r = rem - t*300;
    alphasT[(t*50+k)*300 + r] = muq[idx];
  } else if (idx < 830000){
    int d = idx - 750000; int j = d/100; int i = d - j*100;
    whhH[d] = packh2(whh[j*200 + 2*i], whh[j*200 + 2*i + 1]);
  } else if (idx < 842500){
    int d = idx - 830000; int q = d/125; int i = d - q*125;
    const float* src = (q < 50) ? (muEW + q*250) : (lsEW + (q-50)*250);
    etaWH[d] = packh2(src[2*i], src[2*i+1]);
  } else if (idx < 843300){
    int j = idx - 842500; biasHH[j] = bih[j] + bhh[j];
  } else if (idx < 843556){
    int b = idx - 843300; int t = times[b];
    int pos = atomicAdd(&docCnt[t], 1);
    docList[t*256 + pos] = b;
  }
}

// ---------------- generic NT (row-dot-row) fp32 GEMM, 64x64 tile, kc=32 ----------------
template<bool ATOMIC, bool HALFOUT, bool RELU, bool ABIAS, bool NBIAS>
__global__ __launch_bounds__(256) void nt_gemm(
    const float* __restrict__ A, int lda, const float* __restrict__ B, int ldb,
    float* __restrict__ C, _Float16* __restrict__ Ch, int ldc,
    const float* __restrict__ aBias, const float* __restrict__ nBias,
    int M, int N, int K, int nT, int kS)
{
  __shared__ __align__(16) float As[32*68];
  __shared__ __align__(16) float Bs[32*68];
  int bid = blockIdx.x;
  int kIdx = bid % kS; int nIdx = (bid / kS) % nT; int mIdx = bid / (kS * nT);
  int tid = threadIdx.x;
  int tx = tid & 15, ty = tid >> 4;
  int chunks = (K + 31) >> 5;
  int c0 = (int)(((long long)chunks * kIdx) / kS);
  int c1 = (int)(((long long)chunks * (kIdx+1)) / kS);
  float acc[16];
  #pragma unroll
  for (int i = 0; i < 16; i++) acc[i] = 0.f;
  int sub = tid >> 5, kk = tid & 31;
  for (int c = c0; c < c1; c++){
    int k = (c << 5) + kk;
    bool kok = (k < K);
    float ab = 0.f;
    if (ABIAS) ab = kok ? aBias[k] : 0.f;
    #pragma unroll
    for (int r = 0; r < 8; r++){
      int row = (r << 3) + sub;
      int gm = (mIdx << 6) + row;
      float v = (kok && gm < M) ? (A[(size_t)gm*lda + k] + ab) : 0.f;
      As[kk*68 + row] = v;
      int gn = (nIdx << 6) + row;
      float w = (kok && gn < N) ? B[(size_t)gn*ldb + k] : 0.f;
      Bs[kk*68 + row] = w;
    }
    __syncthreads();
    #pragma unroll
    for (int q = 0; q < 32; q++){
      float4 av = *(const float4*)&As[q*68 + (tx << 2)];
      float4 bv = *(const float4*)&Bs[q*68 + (ty << 2)];
      acc[0]  += av.x*bv.x; acc[1]  += av.x*bv.y; acc[2]  += av.x*bv.z; acc[3]  += av.x*bv.w;
      acc[4]  += av.y*bv.x; acc[5]  += av.y*bv.y; acc[6]  += av.y*bv.z; acc[7]  += av.y*bv.w;
      acc[8]  += av.z*bv.x; acc[9]  += av.z*bv.y; acc[10] += av.z*bv.z; acc[11] += av.z*bv.w;
      acc[12] += av.w*bv.x; acc[13] += av.w*bv.y; acc[14] += av.w*bv.z; acc[15] += av.w*bv.w;
    }
    __syncthreads();
  }
  #pragma unroll
  for (int i = 0; i < 4; i++){
    int gm = (mIdx << 6) + (tx << 2) + i;
    if (gm >= M) continue;
    #pragma unroll
    for (int j = 0; j < 4; j++){
      int gn = (nIdx << 6) + (ty << 2) + j;
      if (gn >= N) continue;
      float v = acc[i*4 + j];
      if (ATOMIC){
        atomicAdd(&C[(size_t)gm*ldc + gn], v);
      } else {
        if (NBIAS) v += nBias[gn];
        if (RELU)  v = fmaxf(v, 0.f);
        if (HALFOUT) Ch[(size_t)gm*ldc + gn] = (_Float16)v;
        else         C[(size_t)gm*ldc + gn] = v;
      }
    }
  }
}

// ---------------- kl_alpha ----------------
__global__ __launch_bounds__(256) void k_klalpha(const float* __restrict__ muq,
                                                 const float* __restrict__ lsq,
                                                 float* __restrict__ W)
{
  __shared__ float red[256];
  const float inv_dl = 1.f/(0.005f + 1e-6f);
  const float logdl = -5.2983173665480363f;
  float local = 0.f;
  for (int idx = blockIdx.x*256 + threadIdx.x; idx < 750000; idx += gridDim.x*256){
    int k = idx / 15000; int rem = idx - k*15000; int t = rem / 300;
    float ls = lsq[idx]; float mu = muq[idx];
    if (t == 0){
      local += 0.5f*((__expf(ls) + mu*mu)/(1.f + 1e-6f) - 1.f - ls);
    } else {
      float d = mu - muq[idx - 300];
      local += 0.5f*((__expf(ls) + d*d)*inv_dl - 1.f + logdl - ls);
    }
  }
  blockReduceAdd(local, red, W + OFF_SCAL + 1);
}

// ---------------- fused LSTM + eta recurrence, one block per source ----------------
// 512 threads: tid<400 own Whh rows (tid, tid+400) as f16 pairs in regs;
// tid<200 also own cell state c; tid in [400,500) own eta weight rows (f16 pairs in regs).
__global__ __launch_bounds__(512) void k_lstm(
    const float* __restrict__ xw, const u32* __restrict__ whhH, const u32* __restrict__ etaWH,
    const float* __restrict__ muEB, const float* __restrict__ lsEB,
    float* __restrict__ etas, float* __restrict__ W)
{
  int s = blockIdx.x; int tid = threadIdx.x;
  __shared__ uint4 hp4[32];      // 128 dwords of f16 pairs: [0..99] h (200 vals), [100..124] eta_prev (50 vals), rest 0
  __shared__ float zbuf[800];
  __shared__ float red[512];
  u32 wreg[200];
  #pragma unroll
  for (int i = 0; i < 200; i++) wreg[i] = 0u;
  if (tid < 400){
    const u32* ra = whhH + tid*100;
    const u32* rb = whhH + (tid + 400)*100;
    #pragma unroll
    for (int i = 0; i < 100; i++){ wreg[i] = ra[i]; wreg[100+i] = rb[i]; }
  } else if (tid < 500){
    int q = tid - 400;
    const u32* re = etaWH + q*125;
    #pragma unroll
    for (int i = 0; i < 125; i++) wreg[i] = re[i];
  }
  float ebias = 0.f;
  if (tid >= 400 && tid < 500){
    int q = tid - 400;
    ebias = (q < 50) ? muEB[q] : lsEB[q - 50];
  }
  float creg = 0.f, muPrev = 0.f, klLocal = 0.f;
  if (tid < 32){ uint4 z; z.x=z.y=z.z=z.w=0u; hp4[tid] = z; }
  __syncthreads();
  const float inv_dl = 1.f/(0.005f + 1e-6f);
  const float logdl = -5.2983173665480363f;
  _Float16* hview = (_Float16*)hp4;

  for (int t = 0; t < NT_T; t++){
    // A: z = xw + Whh @ h
    if (tid < 400){
      float zA = 0.f, zB = 0.f;
      #pragma unroll
      for (int i4 = 0; i4 < 25; i4++){
        uint4 h = hp4[i4];
        zA = dot2u(wreg[i4*4+0], h.x, zA); zA = dot2u(wreg[i4*4+1], h.y, zA);
        zA = dot2u(wreg[i4*4+2], h.z, zA); zA = dot2u(wreg[i4*4+3], h.w, zA);
        zB = dot2u(wreg[100+i4*4+0], h.x, zB); zB = dot2u(wreg[100+i4*4+1], h.y, zB);
        zB = dot2u(wreg[100+i4*4+2], h.z, zB); zB = dot2u(wreg[100+i4*4+3], h.w, zB);
      }
      const float* xr = xw + (size_t)(s*50 + t)*800;
      zbuf[tid]       = zA + xr[tid];
      zbuf[tid + 400] = zB + xr[tid + 400];
    }
    __syncthreads();  // B1
    // C: gates (torch order i,f,g,o)
    if (tid < 200){
      float zi = zbuf[tid], zf = zbuf[200+tid], zg = zbuf[400+tid], zo = zbuf[600+tid];
      float ig = 1.f/(1.f + __expf(-zi));
      float fg = 1.f/(1.f + __expf(-zf));
      float gg = tanhf(zg);
      float og = 1.f/(1.f + __expf(-zo));
      creg = fg*creg + ig*gg;
      float hv = og*tanhf(creg);
      hview[tid] = (_Float16)hv;
    }
    __syncthreads();  // B2
    // D1: eta dots over inp=[h(200), eta_prev(50)]
    float eacc = 0.f;
    bool isEta = (tid >= 400 && tid < 500);
    if (isEta){
      eacc = ebias;
      #pragma unroll
      for (int i4 = 0; i4 < 32; i4++){
        uint4 h = hp4[i4];
        eacc = dot2u(wreg[i4*4+0], h.x, eacc); eacc = dot2u(wreg[i4*4+1], h.y, eacc);
        eacc = dot2u(wreg[i4*4+2], h.z, eacc); eacc = dot2u(wreg[i4*4+3], h.w, eacc);
      }
    }
    __syncthreads();  // B3 (protects hp[100..124] reads vs writes below)
    // D2: commit mu/ls, kl pieces, eta_prev update
    if (isEta){
      int q = tid - 400;
      if (q < 50){
        float mu = eacc;
        etas[(size_t)(s*50 + t)*50 + q] = mu;
        if (t == 0) klLocal += 0.5f*mu*mu/(1.f + 1e-6f);
        else { float d = mu - muPrev; klLocal += 0.5f*d*d*inv_dl; }
        muPrev = mu;
        hview[200 + q] = (_Float16)mu;
      } else {
        float ls = eacc;
        if (t == 0) klLocal += 0.5f*(__expf(ls)/(1.f + 1e-6f) - 1.f - ls);
        else {
          ls = fminf(fmaxf(ls, -10.f), 10.f);
          klLocal += 0.5f*(__expf(ls)*inv_dl - 1.f + logdl - ls);
        }
      }
    }
    // no barrier needed here: next A reads only hp dwords [0..99]; next D1 is after next B1/B2
  }
  __syncthreads();
  blockReduceAdd(klLocal, red, W + OFF_SCAL + 2);
}

// ---------------- per-(t,k) softmax stats over V ----------------
__global__ __launch_bounds__(256) void k_mz(const _Float16* __restrict__ logitH, float* __restrict__ mz)
{
  int r = blockIdx.x; int tid = threadIdx.x;
  const _Float16* row = logitH + (size_t)r*NVOC;
  float m = -1e30f, ssum = 0.f;
  for (int v = tid; v < NVOC; v += 256){
    float l = (float)row[v];
    if (l > m){ ssum = ssum*__expf(m - l) + 1.f; m = l; }
    else ssum += __expf(l - m);
  }
  __shared__ float sm[256], ss[256];
  sm[tid] = m; ss[tid] = ssum; __syncthreads();
  for (int o = 128; o > 0; o >>= 1){
    if (tid < o){
      float m2 = sm[tid+o], s2 = ss[tid+o];
      float M = fmaxf(sm[tid], m2);
      ss[tid] = ss[tid]*__expf(sm[tid] - M) + s2*__expf(m2 - M);
      sm[tid] = M;
    }
    __syncthreads();
  }
  if (tid == 0){ mz[r*2] = sm[0]; mz[r*2+1] = ss[0]; }
}

// ---------------- h1 = relu(hpre + b1 + eta_std @ W1[:,V:]) ----------------
__global__ __launch_bounds__(256) void k_h1(
    const float* __restrict__ hpre, const float* __restrict__ b1, const float* __restrict__ W1,
    const float* __restrict__ etas, const int* __restrict__ times, const int* __restrict__ srcs,
    float* __restrict__ h1)
{
  int b = blockIdx.x, tid = threadIdx.x;
  __shared__ float et[50];
  int tb = times[b], sb = srcs[b];
  if (tid < 50) et[tid] = etas[(size_t)(sb*50 + tb)*50 + tid];
  __syncthreads();
  for (int j = tid; j < 800; j += 256){
    float acc = hpre[(size_t)b*800 + j] + b1[j];
    const float* wrow = W1 + (size_t)j*20050 + 20000;
    #pragma unroll
    for (int k = 0; k < 50; k++) acc += et[k]*wrow[k];
    h1[(size_t)b*800 + j] = fmaxf(acc, 0.f);
  }
}

// ---------------- theta head: mu/ls, softmax, kl_theta, pred, wcoef ----------------
__global__ __launch_bounds__(256) void k_thfin(
    const float* __restrict__ h2g, const float* __restrict__ etas,
    const int* __restrict__ times, const int* __restrict__ srcs,
    const float* __restrict__ muW, const float* __restrict__ muB,
    const float* __restrict__ lsW, const float* __restrict__ lsB,
    const float* __restrict__ clsW, const float* __restrict__ clsB,
    const float* __restrict__ mz, float* __restrict__ wcoef, float* __restrict__ W)
{
  int b = blockIdx.x, tid = threadIdx.x;
  __shared__ float h2s[800], mu[50], lsv[50], et[50], th[50], lg[10], red[64], shm[2];
  for (int j = tid; j < 800; j += 256) h2s[j] = h2g[(size_t)b*800 + j];
  int tb = times[b], sb = srcs[b];
  if (tid < 50) et[tid] = etas[(size_t)(sb*50 + tb)*50 + tid];
  __syncthreads();
  if (tid < 100){
    int q = (tid < 50) ? tid : tid - 50;
    const float* w = (tid < 50) ? (muW + (size_t)q*800) : (lsW + (size_t)q*800);
    float acc = (tid < 50) ? muB[q] : lsB[q];
    #pragma unroll 8
    for (int j = 0; j < 800; j++) acc += h2s[j]*w[j];
    if (tid < 50) mu[q] = acc;
    else lsv[q] = fminf(fmaxf(acc, -10.f), 10.f);
  }
  __syncthreads();
  if (tid == 0){ float m = -1e30f; for (int k = 0; k < 50; k++) m = fmaxf(m, mu[k]); shm[0] = m; }
  __syncthreads();
  if (tid < 50) th[tid] = __expf(mu[tid] - shm[0]);
  __syncthreads();
  if (tid == 0){ float z = 0.f; for (int k = 0; k < 50; k++) z += th[k]; shm[1] = z; }
  __syncthreads();
  if (tid < 64) red[tid] = 0.f;
  if (tid < 50){
    float t_ = th[tid]/shm[1]; th[tid] = t_;
    float m_ = mz[(tb*50 + tid)*2], z_ = mz[(tb*50 + tid)*2 + 1];
    wcoef[(size_t)b*50 + tid] = t_*__expf(-m_)/z_;
    float d = mu[tid] - et[tid];
    red[tid] = 0.5f*((__expf(lsv[tid]) + d*d)/(1.f + 1e-6f) - 1.f - lsv[tid]);
  }
  __syncthreads();
  if (tid < 10){
    float a = clsB[tid];
    #pragma unroll
    for (int k = 0; k < 50; k++) a += th[k]*clsW[tid*50 + k];
    lg[tid] = a;
  }
  __syncthreads();
  if (tid == 0){
    float m = -1e30f; for (int i = 0; i < 10; i++) m = fmaxf(m, lg[i]);
    float z = 0.f; for (int i = 0; i < 10; i++) z += __expf(lg[i] - m);
    float lse = m + __logf(z);
    atomicAdd(W + OFF_SCAL + 4, lse - lg[sb]);
    float ssum = 0.f; for (int i = 0; i < 50; i++) ssum += red[i];
    atomicAdd(W + OFF_SCAL + 3, ssum);
  }
}

// ---------------- nll: blocks over (t, v-chunk), docs bucketed per t ----------------
__global__ __launch_bounds__(256) void k_nll(
    const _Float16* __restrict__ logitH, const float* __restrict__ wcoef,
    const float* __restrict__ bows, float* __restrict__ W)
{
  int t = blockIdx.x/10, vc = blockIdx.x%10;
  int v0 = vc*2000;
  int tid = threadIdx.x;
  const int* docCnt = (const int*)(W + OFF_DOCCNT);
  const int* docList = (const int*)(W + OFF_DOCLIST);
  __shared__ float wch[64*50];
  __shared__ int ids[64];
  __shared__ float red[256];
  int nd = docCnt[t];
  float acc = 0.f;
  for (int d0 = 0; d0 < nd; d0 += 64){
    int ndc = min(64, nd - d0);
    __syncthreads();
    for (int i = tid; i < ndc*50; i += 256){
      int d = i/50, k = i - d*50;
      int bb = docList[t*256 + d0 + d];
      if (k == 0) ids[d] = bb;
      wch[i] = wcoef[(size_t)bb*50 + k];
    }
    __syncthreads();
    for (int v = v0 + tid; v < v0 + 2000; v += 256){
      float e[50];
      #pragma unroll
      for (int k = 0; k < 50; k++)
        e[k] = __expf((float)logitH[(size_t)(t*50 + k)*NVOC + v]);
      for (int d = 0; d < ndc; d++){
        float s = 0.f;
        #pragma unroll
        for (int k = 0; k < 50; k++) s += wch[d*50 + k]*e[k];
        acc += bows[(size_t)ids[d]*NVOC + v]*__logf(s);
      }
    }
  }
  __syncthreads();
  blockReduceAdd(acc, red, W + OFF_SCAL + 0);
}

// ---------------- finalize ----------------
__global__ void k_final(const float* __restrict__ W, const int* __restrict__ ndocs, float* __restrict__ out)
{
  if (blockIdx.x == 0 && threadIdx.x == 0){
    float coeff = (float)ndocs[0] / 256.f;
    const float* scal = W + OFF_SCAL;
    float nll  = -scal[0]*coeff;
    float kla  = scal[1];
    float kle  = scal[2];
    float klth = scal[3]*coeff;
    float pred = scal[4]*coeff;
    out[0] = nll + kla + kle + klth + pred;
    out[1] = nll; out[2] = kla; out[3] = kle; out[4] = klth; out[5] = pred;
  }
}

extern "C" void kernel_launch(void* const* d_in, const int* in_sizes, int n_in,
                              void* d_out, int out_size, void* d_ws, size_t ws_size,
                              hipStream_t stream)
{
  (void)in_sizes; (void)n_in; (void)out_size; (void)ws_size;
  const float* bows  = (const float*)d_in[1];
  const float* nb    = (const float*)d_in[2];
  const int*   times = (const int*)d_in[3];
  const int*   srcs  = (const int*)d_in[4];
  const float* rnn   = (const float*)d_in[5];
  const int*   ndocs = (const int*)d_in[6];
  const float* muq   = (const float*)d_in[7];
  const float* lsq   = (const float*)d_in[8];
  const float* rho   = (const float*)d_in[9];
  const float* W1    = (const float*)d_in[10];
  const float* b1    = (const float*)d_in[11];
  const float* W2    = (const float*)d_in[12];
  const float* b2    = (const float*)d_in[13];
  const float* muthW = (const float*)d_in[14];
  const float* muthB = (const float*)d_in[15];
  const float* lsthW = (const float*)d_in[16];
  const float* lsthB = (const float*)d_in[17];
  const float* emapW = (const float*)d_in[18];
  const float* emapB = (const float*)d_in[19];
  const float* wih   = (const float*)d_in[20];
  const float* whh   = (const float*)d_in[21];
  const float* bih   = (const float*)d_in[22];
  const float* bhh   = (const float*)d_in[23];
  const float* muEW  = (const float*)d_in[24];
  const float* muEB  = (const float*)d_in[25];
  const float* lsEW  = (const float*)d_in[26];
  const float* lsEB  = (const float*)d_in[27];
  const float* clsW  = (const float*)d_in[28];
  const float* clsB  = (const float*)d_in[29];

  float* W = (float*)d_ws;
  _Float16* logitH = (_Float16*)(W + OFF_LOGITH);

  // zero accumulators / atomic targets / doc buckets
  hipMemsetAsync(d_ws, 0, MEMSET_BYTES, stream);

  k_prep<<<3296, 256, 0, stream>>>(muq, whh, muEW, lsEW, bih, bhh, times, W);

  // mapped = rnn @ eta_map_W^T   (atomic split-K)  M=500 N=200 K=20000
  nt_gemm<true,false,false,false,false><<<512, 256, 0, stream>>>(
      rnn, 20000, emapW, 20000, W + OFF_MAPPED, nullptr, 200,
      nullptr, nullptr, 500, 200, 20000, 4, 16);

  // xw = (mapped + eta_map_b) @ Wih^T + (bih+bhh)  M=500 N=800 K=200
  nt_gemm<false,false,false,true,true><<<104, 256, 0, stream>>>(
      W + OFF_MAPPED, 200, wih, 200, W + OFF_XW, nullptr, 800,
      emapB, W + OFF_BIASHH, 500, 800, 200, 13, 1);

  // hpre = nb @ W1[:, :V]^T   (atomic split-K)  M=256 N=800 K=20000 (ldb=20050)
  nt_gemm<true,false,false,false,false><<<416, 256, 0, stream>>>(
      nb, 20000, W1, 20050, W + OFF_HPRE, nullptr, 800,
      nullptr, nullptr, 256, 800, 20000, 13, 8);

  // logit = alphasT @ rho^T -> f16   M=2500 N=20000 K=300
  nt_gemm<false,true,false,false,false><<<12520, 256, 0, stream>>>(
      W + OFF_ALPHAST, 300, rho, 300, nullptr, logitH, 20000,
      nullptr, nullptr, 2500, 20000, 300, 313, 1);

  k_klalpha<<<1024, 256, 0, stream>>>(muq, lsq, W);

  k_lstm<<<NSRC, 512, 0, stream>>>(W + OFF_XW, (const u32*)(W + OFF_WHH_H),
                                   (const u32*)(W + OFF_ETAWH), muEB, lsEB,
                                   W + OFF_ETAS, W);

  k_mz<<<2500, 256, 0, stream>>>(logitH, W + OFF_MZ);

  k_h1<<<256, 256, 0, stream>>>(W + OFF_HPRE, b1, W1, W + OFF_ETAS, times, srcs, W + OFF_H1);

  // h2 = relu(h1 @ W2^T + b2)  M=256 N=800 K=800
  nt_gemm<false,false,true,false,true><<<52, 256, 0, stream>>>(
      W + OFF_H1, 800, W2, 800, W + OFF_H2, nullptr, 800,
      nullptr, b2, 256, 800, 800, 13, 1);

  k_thfin<<<256, 256, 0, stream>>>(W + OFF_H2, W + OFF_ETAS, times, srcs,
                                   muthW, muthB, lsthW, lsthB, clsW, clsB,
                                   W + OFF_MZ, W + OFF_WCOEF, W);

  k_nll<<<500, 256, 0, stream>>>(logitH, W + OFF_WCOEF, bows, W);

  k_final<<<1, 64, 0, stream>>>(W, ndocs, (float*)d_out);
}

// Round 2
// 923.074 us; speedup vs baseline: 2.5250x; 2.5250x over previous
//
#include <hip/hip_runtime.h>

typedef unsigned int u32;
typedef unsigned short ushort_t;

// problem dims
#define NTOP 50
#define NT_T 50
#define NRHO 300
#define NVOC 20000
#define NTH 800
#define NEH 200
#define NSRC 10
#define NBAT 256

// ws offsets (float units)
#define OFF_SCAL     0          // [0]=sum bows*log(s), [1]=kl_alpha, [2]=kl_eta, [3]=kl_theta_raw, [4]=pred_raw
#define OFF_MAPPED   16         // 500*200 fp32 (atomic target)
#define OFF_HPRE     100016     // 256*800 fp32 (atomic target)
#define OFF_DOCCNT   304816     // 50 ints
#define OFF_DOCLIST  304866     // 50*256 ints
#define OFF_XW       317700     // 500*800
#define OFF_BIASHH   717700     // 800
#define OFF_ETAS     718500     // 10*50*50
#define OFF_WCOEF    743500     // 256*50
#define OFF_MZ       756300     // 2500*2
#define OFF_H1       761300     // 256*800
#define OFF_H2       966100     // 256*800
#define OFF_WHH_H    1170900    // 80000 u32 (f16 pairs)
#define OFF_ETAWH    1250900    // 12500 u32
#define OFF_ALPHAB   1263400    // bf16 [2560][320]  = 819200 bf16 = 409600 f
#define OFF_RHOB     1468200    // bf16 [20096][320] = 6430720 bf16 = 3215360 f
#define OFF_NBB      4683560    // bf16 [256][20000] = 2560000 f
// union region at 7243560: {W1B, RNNB, EMWB} then reused by LOGITH
#define OFF_W1B      7243560    // bf16 [896][20000] = 8960000 f
#define OFF_RNNB     16203560   // bf16 [512][20000] = 5120000 f
#define OFF_EMWB     21323560   // bf16 [256][20000] = 2560000 f
#define OFF_LOGITH   7243560    // f16 [2500][20000] = 12500000 f (overwrites W1B/RNNB/EMWB AFTER hpre/mapped gemms)
#define MEMSET_BYTES ((size_t)OFF_XW * 4)
// total ws: 23,883,560 floats = 95.5 MB

typedef _Float16 h2v __attribute__((ext_vector_type(2)));
typedef __bf16 bf16x8 __attribute__((ext_vector_type(8)));
typedef float f32x4 __attribute__((ext_vector_type(4)));

__device__ inline float dot2u(u32 a, u32 b, float c){
  h2v ha = __builtin_bit_cast(h2v, a), hb = __builtin_bit_cast(h2v, b);
#if __has_builtin(__builtin_amdgcn_fdot2)
  return __builtin_amdgcn_fdot2(ha, hb, c, false);
#else
  return c + (float)ha.x*(float)hb.x + (float)ha.y*(float)hb.y;
#endif
}

__device__ inline u32 packh2(float lo, float hi){
  h2v h; h.x = (_Float16)lo; h.y = (_Float16)hi;
  return __builtin_bit_cast(u32, h);
}

__device__ inline ushort_t f2bf(float f){
  u32 u = __builtin_bit_cast(u32, f);
  u = (u + 0x7FFFu + ((u >> 16) & 1u)) >> 16;
  return (ushort_t)u;
}

__device__ __forceinline__ void gl2lds16(const void* g, void* l){
  __builtin_amdgcn_global_load_lds((__attribute__((address_space(1))) void*)g,
                                   (__attribute__((address_space(3))) void*)l,
                                   16, 0, 0);
}

__device__ inline void blockReduceAdd(float v, float* red, float* target){
  int tid = threadIdx.x;
  red[tid] = v; __syncthreads();
  for (int o = blockDim.x >> 1; o > 0; o >>= 1){
    if (tid < o) red[tid] += red[tid + o];
    __syncthreads();
  }
  if (tid == 0) atomicAdd(target, red[0]);
}

// ---------------- prep: f16-pack Whh & eta weights, bias merge, doc buckets --------
__global__ __launch_bounds__(256) void k_prep(
    const float* __restrict__ whh,
    const float* __restrict__ muEW, const float* __restrict__ lsEW,
    const float* __restrict__ bih, const float* __restrict__ bhh,
    const int* __restrict__ times, float* __restrict__ W)
{
  int idx = blockIdx.x*256 + threadIdx.x;
  u32* whhH = (u32*)(W + OFF_WHH_H);
  u32* etaWH = (u32*)(W + OFF_ETAWH);
  float* biasHH = W + OFF_BIASHH;
  int* docCnt = (int*)(W + OFF_DOCCNT);
  int* docList = (int*)(W + OFF_DOCLIST);
  if (idx < 80000){
    int j = idx/100; int i = idx - j*100;
    whhH[idx] = packh2(whh[j*200 + 2*i], whh[j*200 + 2*i + 1]);
  } else if (idx < 92500){
    int d = idx - 80000; int q = d/125; int i = d - q*125;
    const float* src = (q < 50) ? (muEW + q*250) : (lsEW + (q-50)*250);
    etaWH[d] = packh2(src[2*i], src[2*i+1]);
  } else if (idx < 93300){
    int j = idx - 92500; biasHH[j] = bih[j] + bhh[j];
  } else if (idx < 93556){
    int b = idx - 93300; int t = times[b];
    int pos = atomicAdd(&docCnt[t], 1);
    docList[t*256 + pos] = b;
  }
}

// ---------------- generic fp32 -> bf16 padded row-major convert ----------------
__global__ __launch_bounds__(256) void k_conv(const float* __restrict__ src, int ldsrc,
                                              int Mreal, int Kused,
                                              ushort_t* __restrict__ dst, int Mp, int Kp)
{
  int idx = blockIdx.x*256 + threadIdx.x;
  int kb = Kp >> 3;
  if (idx >= Mp*kb) return;
  int row = idx / kb, c = (idx - row*kb) << 3;
  ushort_t out[8];
  #pragma unroll
  for (int j = 0; j < 8; j++){
    float v = 0.f;
    int k = c + j;
    if (row < Mreal && k < Kused) v = src[(size_t)row*ldsrc + k];
    out[j] = f2bf(v);
  }
  *(uint4*)(dst + (size_t)row*Kp + c) = *(uint4*)out;
}

// ---------------- alphas permute + bf16 pad: dst[t*50+k][r] = muq[k][t][r] ----------------
__global__ __launch_bounds__(256) void k_conva(const float* __restrict__ muq, ushort_t* __restrict__ dst)
{
  int idx = blockIdx.x*256 + threadIdx.x;   // 2560*40
  if (idx >= 2560*40) return;
  int row = idx / 40, c = (idx - row*40) << 3;
  ushort_t out[8];
  const float* src = nullptr;
  if (row < 2500){ int t = row/50, k = row - t*50; src = muq + (size_t)k*15000 + t*300; }
  #pragma unroll
  for (int j = 0; j < 8; j++){
    int r = c + j;
    float v = (src && r < 300) ? src[r] : 0.f;
    out[j] = f2bf(v);
  }
  *(uint4*)(dst + (size_t)row*320 + c) = *(uint4*)out;
}

// ---------------- bf16 MFMA NT GEMM: C[M,N] = A[M,K] . B[N,K]^T ----------------
// 128x128 tile, BK=32, 256 thr = 4 waves, per-wave 64x64 via 4x4 16x16x32 frags.
// A,B bf16 padded (rows to tile multiple, K to 32-mult). global_load_lds 16B staging.
template<bool ATOMIC, bool HALFOUT>
__global__ __launch_bounds__(256) void mfma_nt(
    const ushort_t* __restrict__ A, int lda,
    const ushort_t* __restrict__ B, int ldb,
    float* __restrict__ C, _Float16* __restrict__ Ch, int ldc,
    int M, int N, int nT, int kS, int chunks)
{
  __shared__ __align__(16) ushort_t As[128*32];
  __shared__ __align__(16) ushort_t Bs[128*32];
  int bid = blockIdx.x;
  int kIdx = bid % kS; int nIdx = (bid / kS) % nT; int mIdx = bid / (kS * nT);
  int tid = threadIdx.x;
  int w = tid >> 6, l = tid & 63;
  int c0 = (int)(((long long)chunks * kIdx) / kS);
  int c1 = (int)(((long long)chunks * (kIdx+1)) / kS);
  // staging: wave w covers rows [w*32, w*32+32) of each tile, 2 instrs of 16 rows
  int r0 = w*32;
  const ushort_t* ga0 = A + (size_t)(mIdx*128 + r0      + (l>>2))*lda + (l&3)*8;
  const ushort_t* ga1 = A + (size_t)(mIdx*128 + r0 + 16 + (l>>2))*lda + (l&3)*8;
  const ushort_t* gb0 = B + (size_t)(nIdx*128 + r0      + (l>>2))*ldb + (l&3)*8;
  const ushort_t* gb1 = B + (size_t)(nIdx*128 + r0 + 16 + (l>>2))*ldb + (l&3)*8;
  ushort_t* la = As + r0*32;
  ushort_t* lb = Bs + r0*32;
  int wr = (w >> 1)*64, wc = (w & 1)*64;
  int lr = l & 15, lq = l >> 4;
  f32x4 acc[4][4];
  #pragma unroll
  for (int i = 0; i < 4; i++)
    #pragma unroll
    for (int j = 0; j < 4; j++)
      acc[i][j] = (f32x4)0.f;

  for (int c = c0; c < c1; c++){
    size_t ko = (size_t)c * 32;
    gl2lds16(ga0 + ko, la);
    gl2lds16(ga1 + ko, la + 512);
    gl2lds16(gb0 + ko, lb);
    gl2lds16(gb1 + ko, lb + 512);
    __syncthreads();
    bf16x8 av[4], bv[4];
    #pragma unroll
    for (int i = 0; i < 4; i++)
      av[i] = *(const bf16x8*)(As + (wr + i*16 + lr)*32 + lq*8);
    #pragma unroll
    for (int j = 0; j < 4; j++)
      bv[j] = *(const bf16x8*)(Bs + (wc + j*16 + lr)*32 + lq*8);
    #pragma unroll
    for (int i = 0; i < 4; i++)
      #pragma unroll
      for (int j = 0; j < 4; j++)
        acc[i][j] = __builtin_amdgcn_mfma_f32_16x16x32_bf16(av[i], bv[j], acc[i][j], 0, 0, 0);
    __syncthreads();
  }
  // epilogue: D row = wr+i*16+lq*4+r (A-side), col = wc+j*16+lr (B-side)
  #pragma unroll
  for (int i = 0; i < 4; i++){
    #pragma unroll
    for (int r = 0; r < 4; r++){
      int row = mIdx*128 + wr + i*16 + lq*4 + r;
      if (row >= M) continue;
      #pragma unroll
      for (int j = 0; j < 4; j++){
        int col = nIdx*128 + wc + j*16 + lr;
        if (col >= N) continue;
        float v = acc[i][j][r];
        if (ATOMIC) atomicAdd(&C[(size_t)row*ldc + col], v);
        else        Ch[(size_t)row*ldc + col] = (_Float16)v;
      }
    }
  }
}

// ---------------- fp32 NT GEMM (small shapes: xw, h2) ----------------
template<bool RELU, bool ABIAS, bool NBIAS>
__global__ __launch_bounds__(256) void nt_gemm(
    const float* __restrict__ A, int lda, const float* __restrict__ B, int ldb,
    float* __restrict__ C, int ldc,
    const float* __restrict__ aBias, const float* __restrict__ nBias,
    int M, int N, int K, int nT)
{
  __shared__ __align__(16) float As[32*68];
  __shared__ __align__(16) float Bs[32*68];
  int bid = blockIdx.x;
  int nIdx = bid % nT; int mIdx = bid / nT;
  int tid = threadIdx.x;
  int tx = tid & 15, ty = tid >> 4;
  int chunks = (K + 31) >> 5;
  float acc[16];
  #pragma unroll
  for (int i = 0; i < 16; i++) acc[i] = 0.f;
  int sub = tid >> 5, kk = tid & 31;
  for (int c = 0; c < chunks; c++){
    int k = (c << 5) + kk;
    bool kok = (k < K);
    float ab = 0.f;
    if (ABIAS) ab = kok ? aBias[k] : 0.f;
    #pragma unroll
    for (int r = 0; r < 8; r++){
      int row = (r << 3) + sub;
      int gm = (mIdx << 6) + row;
      float v = (kok && gm < M) ? (A[(size_t)gm*lda + k] + ab) : 0.f;
      As[kk*68 + row] = v;
      int gn = (nIdx << 6) + row;
      float wv = (kok && gn < N) ? B[(size_t)gn*ldb + k] : 0.f;
      Bs[kk*68 + row] = wv;
    }
    __syncthreads();
    #pragma unroll
    for (int q = 0; q < 32; q++){
      float4 av = *(const float4*)&As[q*68 + (tx << 2)];
      float4 bv = *(const float4*)&Bs[q*68 + (ty << 2)];
      acc[0]  += av.x*bv.x; acc[1]  += av.x*bv.y; acc[2]  += av.x*bv.z; acc[3]  += av.x*bv.w;
      acc[4]  += av.y*bv.x; acc[5]  += av.y*bv.y; acc[6]  += av.y*bv.z; acc[7]  += av.y*bv.w;
      acc[8]  += av.z*bv.x; acc[9]  += av.z*bv.y; acc[10] += av.z*bv.z; acc[11] += av.z*bv.w;
      acc[12] += av.w*bv.x; acc[13] += av.w*bv.y; acc[14] += av.w*bv.z; acc[15] += av.w*bv.w;
    }
    __syncthreads();
  }
  #pragma unroll
  for (int i = 0; i < 4; i++){
    int gm = (mIdx << 6) + (tx << 2) + i;
    if (gm >= M) continue;
    #pragma unroll
    for (int j = 0; j < 4; j++){
      int gn = (nIdx << 6) + (ty << 2) + j;
      if (gn >= N) continue;
      float v = acc[i*4 + j];
      if (NBIAS) v += nBias[gn];
      if (RELU)  v = fmaxf(v, 0.f);
      C[(size_t)gm*ldc + gn] = v;
    }
  }
}

// ---------------- kl_alpha ----------------
__global__ __launch_bounds__(256) void k_klalpha(const float* __restrict__ muq,
                                                 const float* __restrict__ lsq,
                                                 float* __restrict__ W)
{
  __shared__ float red[256];
  const float inv_dl = 1.f/(0.005f + 1e-6f);
  const float logdl = -5.2983173665480363f;
  float local = 0.f;
  for (int idx = blockIdx.x*256 + threadIdx.x; idx < 750000; idx += gridDim.x*256){
    int k = idx / 15000; int rem = idx - k*15000; int t = rem / 300;
    (void)k;
    float ls = lsq[idx]; float mu = muq[idx];
    if (t == 0){
      local += 0.5f*((__expf(ls) + mu*mu)/(1.f + 1e-6f) - 1.f - ls);
    } else {
      float d = mu - muq[idx - 300];
      local += 0.5f*((__expf(ls) + d*d)*inv_dl - 1.f + logdl - ls);
    }
  }
  blockReduceAdd(local, red, W + OFF_SCAL + 1);
}

// ---------------- fused LSTM + eta recurrence, one block per source ----------------
__global__ __launch_bounds__(512) void k_lstm(
    const float* __restrict__ xw, const u32* __restrict__ whhH, const u32* __restrict__ etaWH,
    const float* __restrict__ muEB, const float* __restrict__ lsEB,
    float* __restrict__ etas, float* __restrict__ W)
{
  int s = blockIdx.x; int tid = threadIdx.x;
  __shared__ uint4 hp4[32];
  __shared__ float zbuf[800];
  __shared__ float red[512];
  u32 wreg[200];
  #pragma unroll
  for (int i = 0; i < 200; i++) wreg[i] = 0u;
  if (tid < 400){
    const u32* ra = whhH + tid*100;
    const u32* rb = whhH + (tid + 400)*100;
    #pragma unroll
    for (int i = 0; i < 100; i++){ wreg[i] = ra[i]; wreg[100+i] = rb[i]; }
  } else if (tid < 500){
    int q = tid - 400;
    const u32* re = etaWH + q*125;
    #pragma unroll
    for (int i = 0; i < 125; i++) wreg[i] = re[i];
  }
  float ebias = 0.f;
  if (tid >= 400 && tid < 500){
    int q = tid - 400;
    ebias = (q < 50) ? muEB[q] : lsEB[q - 50];
  }
  float creg = 0.f, muPrev = 0.f, klLocal = 0.f;
  if (tid < 32){ uint4 z; z.x=z.y=z.z=z.w=0u; hp4[tid] = z; }
  __syncthreads();
  const float inv_dl = 1.f/(0.005f + 1e-6f);
  const float logdl = -5.2983173665480363f;
  _Float16* hview = (_Float16*)hp4;

  for (int t = 0; t < NT_T; t++){
    if (tid < 400){
      float zA = 0.f, zB = 0.f;
      #pragma unroll
      for (int i4 = 0; i4 < 25; i4++){
        uint4 h = hp4[i4];
        zA = dot2u(wreg[i4*4+0], h.x, zA); zA = dot2u(wreg[i4*4+1], h.y, zA);
        zA = dot2u(wreg[i4*4+2], h.z, zA); zA = dot2u(wreg[i4*4+3], h.w, zA);
        zB = dot2u(wreg[100+i4*4+0], h.x, zB); zB = dot2u(wreg[100+i4*4+1], h.y, zB);
        zB = dot2u(wreg[100+i4*4+2], h.z, zB); zB = dot2u(wreg[100+i4*4+3], h.w, zB);
      }
      const float* xr = xw + (size_t)(s*50 + t)*800;
      zbuf[tid]       = zA + xr[tid];
      zbuf[tid + 400] = zB + xr[tid + 400];
    }
    __syncthreads();
    if (tid < 200){
      float zi = zbuf[tid], zf = zbuf[200+tid], zg = zbuf[400+tid], zo = zbuf[600+tid];
      float ig = 1.f/(1.f + __expf(-zi));
      float fg = 1.f/(1.f + __expf(-zf));
      float gg = tanhf(zg);
      float og = 1.f/(1.f + __expf(-zo));
      creg = fg*creg + ig*gg;
      float hv = og*tanhf(creg);
      hview[tid] = (_Float16)hv;
    }
    __syncthreads();
    float eacc = 0.f;
    bool isEta = (tid >= 400 && tid < 500);
    if (isEta){
      eacc = ebias;
      #pragma unroll
      for (int i4 = 0; i4 < 32; i4++){
        uint4 h = hp4[i4];
        eacc = dot2u(wreg[i4*4+0], h.x, eacc); eacc = dot2u(wreg[i4*4+1], h.y, eacc);
        eacc = dot2u(wreg[i4*4+2], h.z, eacc); eacc = dot2u(wreg[i4*4+3], h.w, eacc);
      }
    }
    __syncthreads();
    if (isEta){
      int q = tid - 400;
      if (q < 50){
        float mu = eacc;
        etas[(size_t)(s*50 + t)*50 + q] = mu;
        if (t == 0) klLocal += 0.5f*mu*mu/(1.f + 1e-6f);
        else { float d = mu - muPrev; klLocal += 0.5f*d*d*inv_dl; }
        muPrev = mu;
        hview[200 + q] = (_Float16)mu;
      } else {
        float ls = eacc;
        if (t == 0) klLocal += 0.5f*(__expf(ls)/(1.f + 1e-6f) - 1.f - ls);
        else {
          ls = fminf(fmaxf(ls, -10.f), 10.f);
          klLocal += 0.5f*(__expf(ls)*inv_dl - 1.f + logdl - ls);
        }
      }
    }
  }
  __syncthreads();
  blockReduceAdd(klLocal, red, W + OFF_SCAL + 2);
}

// ---------------- per-(t,k) softmax stats over V (vectorized f16 loads) ----------------
__global__ __launch_bounds__(256) void k_mz(const _Float16* __restrict__ logitH, float* __restrict__ mz)
{
  int r = blockIdx.x; int tid = threadIdx.x;
  const uint4* row = (const uint4*)(logitH + (size_t)r*NVOC);
  float m = -1e30f, ssum = 0.f;
  for (int g = tid; g < 2500; g += 256){
    uint4 pk = row[g];
    _Float16 h[8]; *(uint4*)h = pk;
    #pragma unroll
    for (int j = 0; j < 8; j++){
      float l = (float)h[j];
      if (l > m){ ssum = ssum*__expf(m - l) + 1.f; m = l; }
      else ssum += __expf(l - m);
    }
  }
  __shared__ float sm[256], ss[256];
  sm[tid] = m; ss[tid] = ssum; __syncthreads();
  for (int o = 128; o > 0; o >>= 1){
    if (tid < o){
      float m2 = sm[tid+o], s2 = ss[tid+o];
      float M = fmaxf(sm[tid], m2);
      ss[tid] = ss[tid]*__expf(sm[tid] - M) + s2*__expf(m2 - M);
      sm[tid] = M;
    }
    __syncthreads();
  }
  if (tid == 0){ mz[r*2] = sm[0]; mz[r*2+1] = ss[0]; }
}

// ---------------- h1 = relu(hpre + b1 + eta_std @ W1[:,V:]) ----------------
__global__ __launch_bounds__(256) void k_h1(
    const float* __restrict__ hpre, const float* __restrict__ b1, const float* __restrict__ W1,
    const float* __restrict__ etas, const int* __restrict__ times, const int* __restrict__ srcs,
    float* __restrict__ h1)
{
  int b = blockIdx.x, tid = threadIdx.x;
  __shared__ float et[50];
  int tb = times[b], sb = srcs[b];
  if (tid < 50) et[tid] = etas[(size_t)(sb*50 + tb)*50 + tid];
  __syncthreads();
  for (int j = tid; j < 800; j += 256){
    float acc = hpre[(size_t)b*800 + j] + b1[j];
    const float* wrow = W1 + (size_t)j*20050 + 20000;
    #pragma unroll
    for (int k = 0; k < 50; k++) acc += et[k]*wrow[k];
    h1[(size_t)b*800 + j] = fmaxf(acc, 0.f);
  }
}

// ---------------- theta head ----------------
__global__ __launch_bounds__(256) void k_thfin(
    const float* __restrict__ h2g, const float* __restrict__ etas,
    const int* __restrict__ times, const int* __restrict__ srcs,
    const float* __restrict__ muW, const float* __restrict__ muB,
    const float* __restrict__ lsW, const float* __restrict__ lsB,
    const float* __restrict__ clsW, const float* __restrict__ clsB,
    const float* __restrict__ mz, float* __restrict__ wcoef, float* __restrict__ W)
{
  int b = blockIdx.x, tid = threadIdx.x;
  __shared__ float h2s[800], mu[50], lsv[50], et[50], th[50], lg[10], red[64], shm[2];
  for (int j = tid; j < 800; j += 256) h2s[j] = h2g[(size_t)b*800 + j];
  int tb = times[b], sb = srcs[b];
  if (tid < 50) et[tid] = etas[(size_t)(sb*50 + tb)*50 + tid];
  __syncthreads();
  if (tid < 100){
    int q = (tid < 50) ? tid : tid - 50;
    const float* w = (tid < 50) ? (muW + (size_t)q*800) : (lsW + (size_t)q*800);
    float acc = (tid < 50) ? muB[q] : lsB[q];
    #pragma unroll 8
    for (int j = 0; j < 800; j++) acc += h2s[j]*w[j];
    if (tid < 50) mu[q] = acc;
    else lsv[q] = fminf(fmaxf(acc, -10.f), 10.f);
  }
  __syncthreads();
  if (tid == 0){ float m = -1e30f; for (int k = 0; k < 50; k++) m = fmaxf(m, mu[k]); shm[0] = m; }
  __syncthreads();
  if (tid < 50) th[tid] = __expf(mu[tid] - shm[0]);
  __syncthreads();
  if (tid == 0){ float z = 0.f; for (int k = 0; k < 50; k++) z += th[k]; shm[1] = z; }
  __syncthreads();
  if (tid < 64) red[tid] = 0.f;
  if (tid < 50){
    float t_ = th[tid]/shm[1]; th[tid] = t_;
    float m_ = mz[(tb*50 + tid)*2], z_ = mz[(tb*50 + tid)*2 + 1];
    wcoef[(size_t)b*50 + tid] = t_*__expf(-m_)/z_;
    float d = mu[tid] - et[tid];
    red[tid] = 0.5f*((__expf(lsv[tid]) + d*d)/(1.f + 1e-6f) - 1.f - lsv[tid]);
  }
  __syncthreads();
  if (tid < 10){
    float a = clsB[tid];
    #pragma unroll
    for (int k = 0; k < 50; k++) a += th[k]*clsW[tid*50 + k];
    lg[tid] = a;
  }
  __syncthreads();
  if (tid == 0){
    float m = -1e30f; for (int i = 0; i < 10; i++) m = fmaxf(m, lg[i]);
    float z = 0.f; for (int i = 0; i < 10; i++) z += __expf(lg[i] - m);
    float lse = m + __logf(z);
    atomicAdd(W + OFF_SCAL + 4, lse - lg[sb]);
    float ssum = 0.f; for (int i = 0; i < 50; i++) ssum += red[i];
    atomicAdd(W + OFF_SCAL + 3, ssum);
  }
}

// ---------------- nll ----------------
__global__ __launch_bounds__(256) void k_nll(
    const _Float16* __restrict__ logitH, const float* __restrict__ wcoef,
    const float* __restrict__ bows, float* __restrict__ W)
{
  int t = blockIdx.x/10, vc = blockIdx.x%10;
  int v0 = vc*2000;
  int tid = threadIdx.x;
  const int* docCnt = (const int*)(W + OFF_DOCCNT);
  const int* docList = (const int*)(W + OFF_DOCLIST);
  __shared__ float wch[64*50];
  __shared__ int ids[64];
  __shared__ float red[256];
  int nd = docCnt[t];
  float acc = 0.f;
  for (int d0 = 0; d0 < nd; d0 += 64){
    int ndc = min(64, nd - d0);
    __syncthreads();
    for (int i = tid; i < ndc*50; i += 256){
      int d = i/50, k = i - d*50;
      int bb = docList[t*256 + d0 + d];
      if (k == 0) ids[d] = bb;
      wch[i] = wcoef[(size_t)bb*50 + k];
    }
    __syncthreads();
    for (int v = v0 + tid; v < v0 + 2000; v += 256){
      float e[50];
      #pragma unroll
      for (int k = 0; k < 50; k++)
        e[k] = __expf((float)logitH[(size_t)(t*50 + k)*NVOC + v]);
      for (int d = 0; d < ndc; d++){
        float s = 0.f;
        #pragma unroll
        for (int k = 0; k < 50; k++) s += wch[d*50 + k]*e[k];
        acc += bows[(size_t)ids[d]*NVOC + v]*__logf(s);
      }
    }
  }
  __syncthreads();
  blockReduceAdd(acc, red, W + OFF_SCAL + 0);
}

// ---------------- finalize ----------------
__global__ void k_final(const float* __restrict__ W, const int* __restrict__ ndocs, float* __restrict__ out)
{
  if (blockIdx.x == 0 && threadIdx.x == 0){
    float coeff = (float)ndocs[0] / 256.f;
    const float* scal = W + OFF_SCAL;
    float nll  = -scal[0]*coeff;
    float kla  = scal[1];
    float kle  = scal[2];
    float klth = scal[3]*coeff;
    float pred = scal[4]*coeff;
    out[0] = nll + kla + kle + klth + pred;
    out[1] = nll; out[2] = kla; out[3] = kle; out[4] = klth; out[5] = pred;
  }
}

extern "C" void kernel_launch(void* const* d_in, const int* in_sizes, int n_in,
                              void* d_out, int out_size, void* d_ws, size_t ws_size,
                              hipStream_t stream)
{
  (void)in_sizes; (void)n_in; (void)out_size; (void)ws_size;
  const float* bows  = (const float*)d_in[1];
  const float* nb    = (const float*)d_in[2];
  const int*   times = (const int*)d_in[3];
  const int*   srcs  = (const int*)d_in[4];
  const float* rnn   = (const float*)d_in[5];
  const int*   ndocs = (const int*)d_in[6];
  const float* muq   = (const float*)d_in[7];
  const float* lsq   = (const float*)d_in[8];
  const float* rho   = (const float*)d_in[9];
  const float* W1    = (const float*)d_in[10];
  const float* b1    = (const float*)d_in[11];
  const float* W2    = (const float*)d_in[12];
  const float* b2    = (const float*)d_in[13];
  const float* muthW = (const float*)d_in[14];
  const float* muthB = (const float*)d_in[15];
  const float* lsthW = (const float*)d_in[16];
  const float* lsthB = (const float*)d_in[17];
  const float* emapW = (const float*)d_in[18];
  const float* emapB = (const float*)d_in[19];
  const float* wih   = (const float*)d_in[20];
  const float* whh   = (const float*)d_in[21];
  const float* bih   = (const float*)d_in[22];
  const float* bhh   = (const float*)d_in[23];
  const float* muEW  = (const float*)d_in[24];
  const float* muEB  = (const float*)d_in[25];
  const float* lsEW  = (const float*)d_in[26];
  const float* lsEB  = (const float*)d_in[27];
  const float* clsW  = (const float*)d_in[28];
  const float* clsB  = (const float*)d_in[29];

  float* W = (float*)d_ws;
  ushort_t* alphaB = (ushort_t*)(W + OFF_ALPHAB);
  ushort_t* rhoB   = (ushort_t*)(W + OFF_RHOB);
  ushort_t* nbB    = (ushort_t*)(W + OFF_NBB);
  ushort_t* w1B    = (ushort_t*)(W + OFF_W1B);
  ushort_t* rnnB   = (ushort_t*)(W + OFF_RNNB);
  ushort_t* emwB   = (ushort_t*)(W + OFF_EMWB);
  _Float16* logitH = (_Float16*)(W + OFF_LOGITH);

  hipMemsetAsync(d_ws, 0, MEMSET_BYTES, stream);

  k_prep<<<366, 256, 0, stream>>>(whh, muEW, lsEW, bih, bhh, times, W);

  // bf16 conversions
  k_conva<<<400, 256, 0, stream>>>(muq, alphaB);
  k_conv<<<3140, 256, 0, stream>>>(rho, 300, 20000, 300, rhoB, 20096, 320);
  k_conv<<<2500, 256, 0, stream>>>(nb, 20000, 256, 20000, nbB, 256, 20000);
  k_conv<<<8750, 256, 0, stream>>>(W1, 20050, 800, 20000, w1B, 896, 20000);
  k_conv<<<5000, 256, 0, stream>>>(rnn, 20000, 500, 20000, rnnB, 512, 20000);
  k_conv<<<2500, 256, 0, stream>>>(emapW, 20000, 200, 20000, emwB, 256, 20000);

  // mapped = rnn @ eta_map_W^T  M=500 N=200 K=20000  (split-K atomic)
  mfma_nt<true, false><<<4*2*32, 256, 0, stream>>>(
      rnnB, 20000, emwB, 20000, W + OFF_MAPPED, nullptr, 200,
      500, 200, 2, 32, 625);

  // xw = (mapped + eta_map_b) @ Wih^T + (bih+bhh)  M=500 N=800 K=200
  nt_gemm<false, true, true><<<8*13, 256, 0, stream>>>(
      W + OFF_MAPPED, 200, wih, 200, W + OFF_XW, 800,
      emapB, W + OFF_BIASHH, 500, 800, 200, 13);

  // hpre = nb @ W1[:, :V]^T  M=256 N=800 K=20000  (split-K atomic)
  mfma_nt<true, false><<<2*7*20, 256, 0, stream>>>(
      nbB, 20000, w1B, 20000, W + OFF_HPRE, nullptr, 800,
      256, 800, 7, 20, 625);

  // logit = alphasT @ rho^T -> f16  M=2500 N=20000 K=300 (padded 320)
  // NOTE: writes over w1B/rnnB/emwB region — must run after mapped & hpre gemms.
  mfma_nt<false, true><<<20*157, 256, 0, stream>>>(
      alphaB, 320, rhoB, 320, nullptr, logitH, 20000,
      2500, 20000, 157, 1, 10);

  k_klalpha<<<1024, 256, 0, stream>>>(muq, lsq, W);

  k_lstm<<<NSRC, 512, 0, stream>>>(W + OFF_XW, (const u32*)(W + OFF_WHH_H),
                                   (const u32*)(W + OFF_ETAWH), muEB, lsEB,
                                   W + OFF_ETAS, W);

  k_mz<<<2500, 256, 0, stream>>>(logitH, W + OFF_MZ);

  k_h1<<<256, 256, 0, stream>>>(W + OFF_HPRE, b1, W1, W + OFF_ETAS, times, srcs, W + OFF_H1);

  // h2 = relu(h1 @ W2^T + b2)  M=256 N=800 K=800
  nt_gemm<true, false, true><<<4*13, 256, 0, stream>>>(
      W + OFF_H1, 800, W2, 800, W + OFF_H2, 800,
      nullptr, b2, 256, 800, 800, 13);

  k_thfin<<<256, 256, 0, stream>>>(W + OFF_H2, W + OFF_ETAS, times, srcs,
                                   muthW, muthB, lsthW, lsthB, clsW, clsB,
                                   W + OFF_MZ, W + OFF_WCOEF, W);

  k_nll<<<500, 256, 0, stream>>>(logitH, W + OFF_WCOEF, bows, W);

  k_final<<<1, 64, 0, stream>>>(W, ndocs, (float*)d_out);
}

// Round 3
// 776.992 us; speedup vs baseline: 2.9997x; 1.1880x over previous
//
#include <hip/hip_runtime.h>

typedef unsigned int u32;
typedef unsigned short ushort_t;

// problem dims
#define NTOP 50
#define NT_T 50
#define NRHO 300
#define NVOC 20000
#define NTH 800
#define NEH 200
#define NSRC 10
#define NBAT 256

// ws offsets (float units)
#define OFF_SCAL     0          // [0]=sum bows*log(s), [1]=kl_alpha, [2]=kl_eta, [3]=kl_theta_raw, [4]=pred_raw
#define OFF_MAPPED   16         // 500*200 fp32 (atomic)
#define OFF_HPRE     100016     // 256*800 fp32 (atomic)
#define OFF_H2       304816     // 256*800 fp32 (atomic)
#define OFF_DOCCNT   509616     // 50 ints
#define OFF_DOCLIST  509666     // 50*256 ints
#define MEMSET_BYTES ((size_t)522466 * 4)
#define OFF_XW       522496     // 500*800 fp32
#define OFF_BIAS2    922496     // 800
#define OFF_ETAS     923296     // 10*50*50
#define OFF_WCOEF    948296     // 256*50
#define OFF_MZ       961096     // 2500*2
#define OFF_W1E      966096     // 800*50 fp32 compact W1[:,V:]
#define OFF_WHH_H    1006096    // 80000 u32 (f16 pairs)
#define OFF_ETAWH    1086096    // 12500 u32
#define OFF_H1B      1098596    // bf16 [256][800]   = 102400 f
#define OFF_MAPB     1201000    // bf16 [512][224]   = 57344 f
#define OFF_WIHB     1258344    // bf16 [896][224]   = 100352 f
#define OFF_W2B      1358696    // bf16 [896][800]   = 358400 f
#define OFF_ALPHAB   1717100    // bf16 [2560][320]  = 409600 f
#define OFF_RHOB     2126700    // bf16 [20096][320] = 3215360 f
#define OFF_NBB      5342060    // bf16 [256][20000] = 2560000 f
// union region: {W1B, RNNB, EMWB} reused by LOGITH after mapped/hpre gemms
#define OFF_W1B      7902060    // bf16 [896][20000] = 8960000 f
#define OFF_RNNB     16862060   // bf16 [512][20000] = 5120000 f
#define OFF_EMWB     21982060   // bf16 [256][20000] = 2560000 f
#define OFF_LOGITH   7902060    // f16 [2500][20000] = 12500000 f
// total ws: 24,542,060 floats = 98.2 MB

typedef _Float16 h2v __attribute__((ext_vector_type(2)));
typedef __bf16 bf16x8 __attribute__((ext_vector_type(8)));
typedef float f32x4 __attribute__((ext_vector_type(4)));

__device__ inline float dot2u(u32 a, u32 b, float c){
  h2v ha = __builtin_bit_cast(h2v, a), hb = __builtin_bit_cast(h2v, b);
#if __has_builtin(__builtin_amdgcn_fdot2)
  return __builtin_amdgcn_fdot2(ha, hb, c, false);
#else
  return c + (float)ha.x*(float)hb.x + (float)ha.y*(float)hb.y;
#endif
}

__device__ inline u32 packh2(float lo, float hi){
  h2v h; h.x = (_Float16)lo; h.y = (_Float16)hi;
  return __builtin_bit_cast(u32, h);
}

__device__ inline ushort_t f2bf(float f){
  u32 u = __builtin_bit_cast(u32, f);
  u = (u + 0x7FFFu + ((u >> 16) & 1u)) >> 16;
  return (ushort_t)u;
}

__device__ __forceinline__ void gl2lds16(const void* g, void* l){
  __builtin_amdgcn_global_load_lds((__attribute__((address_space(1))) void*)g,
                                   (__attribute__((address_space(3))) void*)l,
                                   16, 0, 0);
}

__device__ inline void blockReduceAdd(float v, float* red, float* target){
  int tid = threadIdx.x;
  red[tid] = v; __syncthreads();
  for (int o = blockDim.x >> 1; o > 0; o >>= 1){
    if (tid < o) red[tid] += red[tid + o];
    __syncthreads();
  }
  if (tid == 0) atomicAdd(target, red[0]);
}

// ---------------- prep: f16 packs, bias2, W1E compact, doc buckets ----------------
__global__ __launch_bounds__(256) void k_prep(
    const float* __restrict__ whh,
    const float* __restrict__ muEW, const float* __restrict__ lsEW,
    const float* __restrict__ bih, const float* __restrict__ bhh,
    const float* __restrict__ wih, const float* __restrict__ emapB,
    const float* __restrict__ W1, const int* __restrict__ times,
    float* __restrict__ W)
{
  int idx = blockIdx.x*256 + threadIdx.x;
  u32* whhH = (u32*)(W + OFF_WHH_H);
  u32* etaWH = (u32*)(W + OFF_ETAWH);
  float* bias2 = W + OFF_BIAS2;
  float* w1e = W + OFF_W1E;
  int* docCnt = (int*)(W + OFF_DOCCNT);
  int* docList = (int*)(W + OFF_DOCLIST);
  if (idx < 80000){
    int j = idx/100; int i = idx - j*100;
    whhH[idx] = packh2(whh[j*200 + 2*i], whh[j*200 + 2*i + 1]);
  } else if (idx < 92500){
    int d = idx - 80000; int q = d/125; int i = d - q*125;
    const float* src = (q < 50) ? (muEW + q*250) : (lsEW + (q-50)*250);
    etaWH[d] = packh2(src[2*i], src[2*i+1]);
  } else if (idx < 93300){
    int j = idx - 92500;
    float acc = bih[j] + bhh[j];
    const float* wr = wih + (size_t)j*200;
    #pragma unroll 4
    for (int k = 0; k < 200; k++) acc += emapB[k]*wr[k];
    bias2[j] = acc;
  } else if (idx < 133300){
    int d = idx - 93300; int j = d/50; int k = d - j*50;
    w1e[d] = W1[(size_t)j*20050 + 20000 + k];
  } else if (idx < 133556){
    int b = idx - 133300; int t = times[b];
    int pos = atomicAdd(&docCnt[t], 1);
    docList[t*256 + pos] = b;
  }
}

// ---------------- generic fp32 -> bf16 padded row-major convert ----------------
__global__ __launch_bounds__(256) void k_conv(const float* __restrict__ src, int ldsrc,
                                              int Mreal, int Kused,
                                              ushort_t* __restrict__ dst, int Mp, int Kp)
{
  int idx = blockIdx.x*256 + threadIdx.x;
  int kb = Kp >> 3;
  if (idx >= Mp*kb) return;
  int row = idx / kb, c = (idx - row*kb) << 3;
  ushort_t out[8];
  #pragma unroll
  for (int j = 0; j < 8; j++){
    float v = 0.f;
    int k = c + j;
    if (row < Mreal && k < Kused) v = src[(size_t)row*ldsrc + k];
    out[j] = f2bf(v);
  }
  *(uint4*)(dst + (size_t)row*Kp + c) = *(uint4*)out;
}

// ---------------- alphas permute + bf16 pad ----------------
__global__ __launch_bounds__(256) void k_conva(const float* __restrict__ muq, ushort_t* __restrict__ dst)
{
  int idx = blockIdx.x*256 + threadIdx.x;
  if (idx >= 2560*40) return;
  int row = idx / 40, c = (idx - row*40) << 3;
  ushort_t out[8];
  const float* src = nullptr;
  if (row < 2500){ int t = row/50, k = row - t*50; src = muq + (size_t)k*15000 + t*300; }
  #pragma unroll
  for (int j = 0; j < 8; j++){
    int r = c + j;
    float v = (src && r < 300) ? src[r] : 0.f;
    out[j] = f2bf(v);
  }
  *(uint4*)(dst + (size_t)row*320 + c) = *(uint4*)out;
}

// ---------------- bf16 MFMA NT GEMM: C[M,N] = A[M,K] . B[N,K]^T ----------------
// MODE 0: atomic f32; MODE 1: f16 store; MODE 2: f32 store + col-bias
template<int MODE>
__global__ __launch_bounds__(256) void mfma_nt(
    const ushort_t* __restrict__ A, int lda,
    const ushort_t* __restrict__ B, int ldb,
    float* __restrict__ C, _Float16* __restrict__ Ch, int ldc,
    const float* __restrict__ nBias,
    int M, int N, int nT, int kS, int chunks)
{
  __shared__ __align__(16) ushort_t As[128*32];
  __shared__ __align__(16) ushort_t Bs[128*32];
  int bid = blockIdx.x;
  int kIdx = bid % kS; int nIdx = (bid / kS) % nT; int mIdx = bid / (kS * nT);
  int tid = threadIdx.x;
  int w = tid >> 6, l = tid & 63;
  int c0 = (int)(((long long)chunks * kIdx) / kS);
  int c1 = (int)(((long long)chunks * (kIdx+1)) / kS);
  int r0 = w*32;
  const ushort_t* ga0 = A + (size_t)(mIdx*128 + r0      + (l>>2))*lda + (l&3)*8;
  const ushort_t* ga1 = A + (size_t)(mIdx*128 + r0 + 16 + (l>>2))*lda + (l&3)*8;
  const ushort_t* gb0 = B + (size_t)(nIdx*128 + r0      + (l>>2))*ldb + (l&3)*8;
  const ushort_t* gb1 = B + (size_t)(nIdx*128 + r0 + 16 + (l>>2))*ldb + (l&3)*8;
  ushort_t* la = As + r0*32;
  ushort_t* lb = Bs + r0*32;
  int wr = (w >> 1)*64, wc = (w & 1)*64;
  int lr = l & 15, lq = l >> 4;
  f32x4 acc[4][4];
  #pragma unroll
  for (int i = 0; i < 4; i++)
    #pragma unroll
    for (int j = 0; j < 4; j++)
      acc[i][j] = (f32x4)0.f;

  for (int c = c0; c < c1; c++){
    size_t ko = (size_t)c * 32;
    gl2lds16(ga0 + ko, la);
    gl2lds16(ga1 + ko, la + 512);
    gl2lds16(gb0 + ko, lb);
    gl2lds16(gb1 + ko, lb + 512);
    __syncthreads();
    bf16x8 av[4], bv[4];
    #pragma unroll
    for (int i = 0; i < 4; i++)
      av[i] = *(const bf16x8*)(As + (wr + i*16 + lr)*32 + lq*8);
    #pragma unroll
    for (int j = 0; j < 4; j++)
      bv[j] = *(const bf16x8*)(Bs + (wc + j*16 + lr)*32 + lq*8);
    #pragma unroll
    for (int i = 0; i < 4; i++)
      #pragma unroll
      for (int j = 0; j < 4; j++)
        acc[i][j] = __builtin_amdgcn_mfma_f32_16x16x32_bf16(av[i], bv[j], acc[i][j], 0, 0, 0);
    __syncthreads();
  }
  #pragma unroll
  for (int i = 0; i < 4; i++){
    #pragma unroll
    for (int r = 0; r < 4; r++){
      int row = mIdx*128 + wr + i*16 + lq*4 + r;
      if (row >= M) continue;
      #pragma unroll
      for (int j = 0; j < 4; j++){
        int col = nIdx*128 + wc + j*16 + lr;
        if (col >= N) continue;
        float v = acc[i][j][r];
        if (MODE == 0)      atomicAdd(&C[(size_t)row*ldc + col], v);
        else if (MODE == 1) Ch[(size_t)row*ldc + col] = (_Float16)v;
        else                C[(size_t)row*ldc + col] = v + nBias[col];
      }
    }
  }
}

// ---------------- kl_alpha ----------------
__global__ __launch_bounds__(256) void k_klalpha(const float* __restrict__ muq,
                                                 const float* __restrict__ lsq,
                                                 float* __restrict__ W)
{
  __shared__ float red[256];
  const float inv_dl = 1.f/(0.005f + 1e-6f);
  const float logdl = -5.2983173665480363f;
  float local = 0.f;
  for (int idx = blockIdx.x*256 + threadIdx.x; idx < 750000; idx += gridDim.x*256){
    int rem = idx % 15000; int t = rem / 300;
    float ls = lsq[idx]; float mu = muq[idx];
    if (t == 0){
      local += 0.5f*((__expf(ls) + mu*mu)/(1.f + 1e-6f) - 1.f - ls);
    } else {
      float d = mu - muq[idx - 300];
      local += 0.5f*((__expf(ls) + d*d)*inv_dl - 1.f + logdl - ls);
    }
  }
  blockReduceAdd(local, red, W + OFF_SCAL + 1);
}

// ---------------- fused LSTM + eta recurrence, one block per source ----------------
__global__ __launch_bounds__(512) void k_lstm(
    const float* __restrict__ xw, const u32* __restrict__ whhH, const u32* __restrict__ etaWH,
    const float* __restrict__ muEB, const float* __restrict__ lsEB,
    float* __restrict__ etas, float* __restrict__ W)
{
  int s = blockIdx.x; int tid = threadIdx.x;
  __shared__ uint4 hp4[32];
  __shared__ float zbuf[800];
  __shared__ float red[512];
  u32 wreg[200];
  #pragma unroll
  for (int i = 0; i < 200; i++) wreg[i] = 0u;
  if (tid < 400){
    const u32* ra = whhH + tid*100;
    const u32* rb = whhH + (tid + 400)*100;
    #pragma unroll
    for (int i = 0; i < 100; i++){ wreg[i] = ra[i]; wreg[100+i] = rb[i]; }
  } else if (tid < 500){
    int q = tid - 400;
    const u32* re = etaWH + q*125;
    #pragma unroll
    for (int i = 0; i < 125; i++) wreg[i] = re[i];
  }
  float ebias = 0.f;
  if (tid >= 400 && tid < 500){
    int q = tid - 400;
    ebias = (q < 50) ? muEB[q] : lsEB[q - 50];
  }
  float creg = 0.f, muPrev = 0.f, klLocal = 0.f;
  if (tid < 32){ uint4 z; z.x=z.y=z.z=z.w=0u; hp4[tid] = z; }
  __syncthreads();
  const float inv_dl = 1.f/(0.005f + 1e-6f);
  const float logdl = -5.2983173665480363f;
  _Float16* hview = (_Float16*)hp4;

  for (int t = 0; t < NT_T; t++){
    if (tid < 400){
      float zA = 0.f, zB = 0.f;
      #pragma unroll
      for (int i4 = 0; i4 < 25; i4++){
        uint4 h = hp4[i4];
        zA = dot2u(wreg[i4*4+0], h.x, zA); zA = dot2u(wreg[i4*4+1], h.y, zA);
        zA = dot2u(wreg[i4*4+2], h.z, zA); zA = dot2u(wreg[i4*4+3], h.w, zA);
        zB = dot2u(wreg[100+i4*4+0], h.x, zB); zB = dot2u(wreg[100+i4*4+1], h.y, zB);
        zB = dot2u(wreg[100+i4*4+2], h.z, zB); zB = dot2u(wreg[100+i4*4+3], h.w, zB);
      }
      const float* xr = xw + (size_t)(s*50 + t)*800;
      zbuf[tid]       = zA + xr[tid];
      zbuf[tid + 400] = zB + xr[tid + 400];
    }
    __syncthreads();
    if (tid < 200){
      float zi = zbuf[tid], zf = zbuf[200+tid], zg = zbuf[400+tid], zo = zbuf[600+tid];
      float ig = 1.f/(1.f + __expf(-zi));
      float fg = 1.f/(1.f + __expf(-zf));
      float gg = tanhf(zg);
      float og = 1.f/(1.f + __expf(-zo));
      creg = fg*creg + ig*gg;
      float hv = og*tanhf(creg);
      hview[tid] = (_Float16)hv;
    }
    __syncthreads();
    float eacc = 0.f;
    bool isEta = (tid >= 400 && tid < 500);
    if (isEta){
      eacc = ebias;
      #pragma unroll
      for (int i4 = 0; i4 < 32; i4++){
        uint4 h = hp4[i4];
        eacc = dot2u(wreg[i4*4+0], h.x, eacc); eacc = dot2u(wreg[i4*4+1], h.y, eacc);
        eacc = dot2u(wreg[i4*4+2], h.z, eacc); eacc = dot2u(wreg[i4*4+3], h.w, eacc);
      }
    }
    __syncthreads();
    if (isEta){
      int q = tid - 400;
      if (q < 50){
        float mu = eacc;
        etas[(size_t)(s*50 + t)*50 + q] = mu;
        if (t == 0) klLocal += 0.5f*mu*mu/(1.f + 1e-6f);
        else { float d = mu - muPrev; klLocal += 0.5f*d*d*inv_dl; }
        muPrev = mu;
        hview[200 + q] = (_Float16)mu;
      } else {
        float ls = eacc;
        if (t == 0) klLocal += 0.5f*(__expf(ls)/(1.f + 1e-6f) - 1.f - ls);
        else {
          ls = fminf(fmaxf(ls, -10.f), 10.f);
          klLocal += 0.5f*(__expf(ls)*inv_dl - 1.f + logdl - ls);
        }
      }
    }
  }
  __syncthreads();
  blockReduceAdd(klLocal, red, W + OFF_SCAL + 2);
}

// ---------------- per-(t,k) softmax stats over V ----------------
__global__ __launch_bounds__(256) void k_mz(const _Float16* __restrict__ logitH, float* __restrict__ mz)
{
  int r = blockIdx.x; int tid = threadIdx.x;
  const uint4* row = (const uint4*)(logitH + (size_t)r*NVOC);
  float m = -1e30f, ssum = 0.f;
  for (int g = tid; g < 2500; g += 256){
    uint4 pk = row[g];
    _Float16 h[8]; *(uint4*)h = pk;
    #pragma unroll
    for (int j = 0; j < 8; j++){
      float l = (float)h[j];
      if (l > m){ ssum = ssum*__expf(m - l) + 1.f; m = l; }
      else ssum += __expf(l - m);
    }
  }
  __shared__ float sm[256], ss[256];
  sm[tid] = m; ss[tid] = ssum; __syncthreads();
  for (int o = 128; o > 0; o >>= 1){
    if (tid < o){
      float m2 = sm[tid+o], s2 = ss[tid+o];
      float M = fmaxf(sm[tid], m2);
      ss[tid] = ss[tid]*__expf(sm[tid] - M) + s2*__expf(m2 - M);
      sm[tid] = M;
    }
    __syncthreads();
  }
  if (tid == 0){ mz[r*2] = sm[0]; mz[r*2+1] = ss[0]; }
}

// ---------------- h1 = relu(hpre + b1 + eta_std @ W1E^T) -> bf16 ----------------
__global__ __launch_bounds__(256) void k_h1(
    const float* __restrict__ hpre, const float* __restrict__ b1, const float* __restrict__ w1e,
    const float* __restrict__ etas, const int* __restrict__ times, const int* __restrict__ srcs,
    ushort_t* __restrict__ h1B)
{
  int b = blockIdx.x, tid = threadIdx.x;
  __shared__ float et[50];
  int tb = times[b], sb = srcs[b];
  if (tid < 50) et[tid] = etas[(size_t)(sb*50 + tb)*50 + tid];
  __syncthreads();
  for (int j = tid; j < 800; j += 256){
    float acc = hpre[(size_t)b*800 + j] + b1[j];
    const float* wrow = w1e + (size_t)j*50;
    #pragma unroll
    for (int k = 0; k < 50; k++) acc += et[k]*wrow[k];
    h1B[(size_t)b*800 + j] = f2bf(fmaxf(acc, 0.f));
  }
}

// ---------------- theta head (h2pre + b2, relu folded here) ----------------
__global__ __launch_bounds__(256) void k_thfin(
    const float* __restrict__ h2g, const float* __restrict__ b2, const float* __restrict__ etas,
    const int* __restrict__ times, const int* __restrict__ srcs,
    const float* __restrict__ muW, const float* __restrict__ muB,
    const float* __restrict__ lsW, const float* __restrict__ lsB,
    const float* __restrict__ clsW, const float* __restrict__ clsB,
    const float* __restrict__ mz, float* __restrict__ wcoef, float* __restrict__ W)
{
  int b = blockIdx.x, tid = threadIdx.x;
  __shared__ float h2s[800], mu[50], lsv[50], et[50], th[50], lg[10], red[64], shm[2];
  for (int j = tid; j < 800; j += 256) h2s[j] = fmaxf(h2g[(size_t)b*800 + j] + b2[j], 0.f);
  int tb = times[b], sb = srcs[b];
  if (tid < 50) et[tid] = etas[(size_t)(sb*50 + tb)*50 + tid];
  __syncthreads();
  if (tid < 100){
    int q = (tid < 50) ? tid : tid - 50;
    const float* w = (tid < 50) ? (muW + (size_t)q*800) : (lsW + (size_t)q*800);
    float acc = (tid < 50) ? muB[q] : lsB[q];
    #pragma unroll 8
    for (int j = 0; j < 800; j++) acc += h2s[j]*w[j];
    if (tid < 50) mu[q] = acc;
    else lsv[q] = fminf(fmaxf(acc, -10.f), 10.f);
  }
  __syncthreads();
  if (tid == 0){ float m = -1e30f; for (int k = 0; k < 50; k++) m = fmaxf(m, mu[k]); shm[0] = m; }
  __syncthreads();
  if (tid < 50) th[tid] = __expf(mu[tid] - shm[0]);
  __syncthreads();
  if (tid == 0){ float z = 0.f; for (int k = 0; k < 50; k++) z += th[k]; shm[1] = z; }
  __syncthreads();
  if (tid < 64) red[tid] = 0.f;
  if (tid < 50){
    float t_ = th[tid]/shm[1]; th[tid] = t_;
    float m_ = mz[(tb*50 + tid)*2], z_ = mz[(tb*50 + tid)*2 + 1];
    wcoef[(size_t)b*50 + tid] = t_*__expf(-m_)/z_;
    float d = mu[tid] - et[tid];
    red[tid] = 0.5f*((__expf(lsv[tid]) + d*d)/(1.f + 1e-6f) - 1.f - lsv[tid]);
  }
  __syncthreads();
  if (tid < 10){
    float a = clsB[tid];
    #pragma unroll
    for (int k = 0; k < 50; k++) a += th[k]*clsW[tid*50 + k];
    lg[tid] = a;
  }
  __syncthreads();
  if (tid == 0){
    float m = -1e30f; for (int i = 0; i < 10; i++) m = fmaxf(m, lg[i]);
    float z = 0.f; for (int i = 0; i < 10; i++) z += __expf(lg[i] - m);
    float lse = m + __logf(z);
    atomicAdd(W + OFF_SCAL + 4, lse - lg[sb]);
    float ssum = 0.f; for (int i = 0; i < 50; i++) ssum += red[i];
    atomicAdd(W + OFF_SCAL + 3, ssum);
  }
}

// ---------------- nll ----------------
__global__ __launch_bounds__(256) void k_nll(
    const _Float16* __restrict__ logitH, const float* __restrict__ wcoef,
    const float* __restrict__ bows, float* __restrict__ W)
{
  int t = blockIdx.x/10, vc = blockIdx.x%10;
  int v0 = vc*2000;
  int tid = threadIdx.x;
  const int* docCnt = (const int*)(W + OFF_DOCCNT);
  const int* docList = (const int*)(W + OFF_DOCLIST);
  __shared__ float wch[64*50];
  __shared__ int ids[64];
  __shared__ float red[256];
  int nd = docCnt[t];
  float acc = 0.f;
  for (int d0 = 0; d0 < nd; d0 += 64){
    int ndc = min(64, nd - d0);
    __syncthreads();
    for (int i = tid; i < ndc*50; i += 256){
      int d = i/50, k = i - d*50;
      int bb = docList[t*256 + d0 + d];
      if (k == 0) ids[d] = bb;
      wch[i] = wcoef[(size_t)bb*50 + k];
    }
    __syncthreads();
    for (int v = v0 + tid; v < v0 + 2000; v += 256){
      float e[50];
      #pragma unroll
      for (int k = 0; k < 50; k++)
        e[k] = __expf((float)logitH[(size_t)(t*50 + k)*NVOC + v]);
      for (int d = 0; d < ndc; d++){
        float s = 0.f;
        #pragma unroll
        for (int k = 0; k < 50; k++) s += wch[d*50 + k]*e[k];
        acc += bows[(size_t)ids[d]*NVOC + v]*__logf(s);
      }
    }
  }
  __syncthreads();
  blockReduceAdd(acc, red, W + OFF_SCAL + 0);
}

// ---------------- finalize ----------------
__global__ void k_final(const float* __restrict__ W, const int* __restrict__ ndocs, float* __restrict__ out)
{
  if (blockIdx.x == 0 && threadIdx.x == 0){
    float coeff = (float)ndocs[0] / 256.f;
    const float* scal = W + OFF_SCAL;
    float nll  = -scal[0]*coeff;
    float kla  = scal[1];
    float kle  = scal[2];
    float klth = scal[3]*coeff;
    float pred = scal[4]*coeff;
    out[0] = nll + kla + kle + klth + pred;
    out[1] = nll; out[2] = kla; out[3] = kle; out[4] = klth; out[5] = pred;
  }
}

extern "C" void kernel_launch(void* const* d_in, const int* in_sizes, int n_in,
                              void* d_out, int out_size, void* d_ws, size_t ws_size,
                              hipStream_t stream)
{
  (void)in_sizes; (void)n_in; (void)out_size; (void)ws_size;
  const float* bows  = (const float*)d_in[1];
  const float* nb    = (const float*)d_in[2];
  const int*   times = (const int*)d_in[3];
  const int*   srcs  = (const int*)d_in[4];
  const float* rnn   = (const float*)d_in[5];
  const int*   ndocs = (const int*)d_in[6];
  const float* muq   = (const float*)d_in[7];
  const float* lsq   = (const float*)d_in[8];
  const float* rho   = (const float*)d_in[9];
  const float* W1    = (const float*)d_in[10];
  const float* b1    = (const float*)d_in[11];
  const float* W2    = (const float*)d_in[12];
  const float* b2    = (const float*)d_in[13];
  const float* muthW = (const float*)d_in[14];
  const float* muthB = (const float*)d_in[15];
  const float* lsthW = (const float*)d_in[16];
  const float* lsthB = (const float*)d_in[17];
  const float* emapW = (const float*)d_in[18];
  const float* emapB = (const float*)d_in[19];
  const float* wih   = (const float*)d_in[20];
  const float* whh   = (const float*)d_in[21];
  const float* bih   = (const float*)d_in[22];
  const float* bhh   = (const float*)d_in[23];
  const float* muEW  = (const float*)d_in[24];
  const float* muEB  = (const float*)d_in[25];
  const float* lsEW  = (const float*)d_in[26];
  const float* lsEB  = (const float*)d_in[27];
  const float* clsW  = (const float*)d_in[28];
  const float* clsB  = (const float*)d_in[29];

  float* W = (float*)d_ws;
  ushort_t* alphaB = (ushort_t*)(W + OFF_ALPHAB);
  ushort_t* rhoB   = (ushort_t*)(W + OFF_RHOB);
  ushort_t* nbB    = (ushort_t*)(W + OFF_NBB);
  ushort_t* w1B    = (ushort_t*)(W + OFF_W1B);
  ushort_t* rnnB   = (ushort_t*)(W + OFF_RNNB);
  ushort_t* emwB   = (ushort_t*)(W + OFF_EMWB);
  ushort_t* wihB   = (ushort_t*)(W + OFF_WIHB);
  ushort_t* w2B    = (ushort_t*)(W + OFF_W2B);
  ushort_t* mapB   = (ushort_t*)(W + OFF_MAPB);
  ushort_t* h1B    = (ushort_t*)(W + OFF_H1B);
  _Float16* logitH = (_Float16*)(W + OFF_LOGITH);

  hipMemsetAsync(d_ws, 0, MEMSET_BYTES, stream);

  k_prep<<<522, 256, 0, stream>>>(whh, muEW, lsEW, bih, bhh, wih, emapB, W1, times, W);

  // bf16 conversions
  k_conva<<<400, 256, 0, stream>>>(muq, alphaB);
  k_conv<<<3140, 256, 0, stream>>>(rho, 300, 20000, 300, rhoB, 20096, 320);
  k_conv<<<2500, 256, 0, stream>>>(nb, 20000, 256, 20000, nbB, 256, 20000);
  k_conv<<<8750, 256, 0, stream>>>(W1, 20050, 800, 20000, w1B, 896, 20000);
  k_conv<<<5000, 256, 0, stream>>>(rnn, 20000, 500, 20000, rnnB, 512, 20000);
  k_conv<<<2500, 256, 0, stream>>>(emapW, 20000, 200, 20000, emwB, 256, 20000);
  k_conv<<<98, 256, 0, stream>>>(wih, 200, 800, 200, wihB, 896, 224);
  k_conv<<<350, 256, 0, stream>>>(W2, 800, 800, 800, w2B, 896, 800);

  // mapped = rnn @ eta_map_W^T  M=500 N=200 K=20000  (split-K atomic)
  mfma_nt<0><<<4*2*32, 256, 0, stream>>>(
      rnnB, 20000, emwB, 20000, W + OFF_MAPPED, nullptr, 200, nullptr,
      500, 200, 2, 32, 625);

  // hpre = nb @ W1[:, :V]^T  M=256 N=800 K=20000  (split-K atomic)
  mfma_nt<0><<<2*7*20, 256, 0, stream>>>(
      nbB, 20000, w1B, 20000, W + OFF_HPRE, nullptr, 800, nullptr,
      256, 800, 7, 20, 625);

  // logit = alphasT @ rho^T -> f16  M=2500 N=20000 K=320 (after w1B/rnnB/emwB consumed)
  mfma_nt<1><<<20*157, 256, 0, stream>>>(
      alphaB, 320, rhoB, 320, nullptr, logitH, 20000, nullptr,
      2500, 20000, 157, 1, 10);

  // mapped -> bf16 [512][224]
  k_conv<<<56, 256, 0, stream>>>(W + OFF_MAPPED, 200, 500, 200, mapB, 512, 224);

  // xw = mapped @ wih^T + bias2  M=500 N=800 K=224
  mfma_nt<2><<<4*7, 256, 0, stream>>>(
      mapB, 224, wihB, 224, W + OFF_XW, nullptr, 800, W + OFF_BIAS2,
      500, 800, 7, 1, 7);

  k_klalpha<<<1024, 256, 0, stream>>>(muq, lsq, W);

  k_lstm<<<NSRC, 512, 0, stream>>>(W + OFF_XW, (const u32*)(W + OFF_WHH_H),
                                   (const u32*)(W + OFF_ETAWH), muEB, lsEB,
                                   W + OFF_ETAS, W);

  k_mz<<<2500, 256, 0, stream>>>(logitH, W + OFF_MZ);

  k_h1<<<256, 256, 0, stream>>>(W + OFF_HPRE, b1, W + OFF_W1E, W + OFF_ETAS, times, srcs, h1B);

  // h2pre = h1 @ W2^T  M=256 N=800 K=800  (split-K atomic; b2+relu folded into k_thfin)
  mfma_nt<0><<<2*7*2, 256, 0, stream>>>(
      h1B, 800, w2B, 800, W + OFF_H2, nullptr, 800, nullptr,
      256, 800, 7, 2, 25);

  k_thfin<<<256, 256, 0, stream>>>(W + OFF_H2, b2, W + OFF_ETAS, times, srcs,
                                   muthW, muthB, lsthW, lsthB, clsW, clsB,
                                   W + OFF_MZ, W + OFF_WCOEF, W);

  k_nll<<<500, 256, 0, stream>>>(logitH, W + OFF_WCOEF, bows, W);

  k_final<<<1, 64, 0, stream>>>(W, ndocs, (float*)d_out);
}

// Round 4
// 733.907 us; speedup vs baseline: 3.1758x; 1.0587x over previous
//
#include <hip/hip_runtime.h>

typedef unsigned int u32;
typedef unsigned short ushort_t;

// problem dims
#define NTOP 50
#define NT_T 50
#define NRHO 300
#define NVOC 20000
#define NTH 800
#define NEH 200
#define NSRC 10
#define NBAT 256

// ws offsets (float units), all 8-float (32B) aligned
#define OFF_SCAL     0          // 5 accumulators
#define OFF_MAPPED   16         // 500*200 fp32 (atomic)
#define OFF_HPRE     100016     // 256*800 fp32 (atomic)
#define OFF_H2       304816     // 256*800 fp32 (atomic)
#define OFF_Z        509616     // 2500 fp32 (atomic row-sums of E)
#define OFF_DOCCNT   512120     // 50 ints
#define OFF_DOCLIST  512176     // 50*256 ints
#define MEMSET_BYTES ((size_t)524976 * 4)
#define OFF_XW       524976     // 500*800 fp32
#define OFF_BIAS2    924976     // 800
#define OFF_ETAS     925776     // 10*50*50
#define OFF_WCOEF    950776     // 256*50
#define OFF_W1E      963576     // 800*50 compact W1[:,V:]
#define OFF_WHH_H    1003576    // 80000 u32 (f16 pairs)
#define OFF_ETAWH    1083576    // 12500 u32
#define OFF_H1B      1096080    // bf16 [256][800]
#define OFF_MAPB     1198480    // bf16 [512][224]
#define OFF_WIHB     1255824    // bf16 [896][224]
#define OFF_W2B      1356176    // bf16 [896][800]
#define OFF_ALPHAB   1714576    // bf16 [2560][320]
#define OFF_RHOB     2124176    // bf16 [20096][320]
#define OFF_NBB      5339536    // bf16 [256][20000]
// union: {W1B, RNNB, EMWB} reused by E (LOGITH) after mapped/hpre gemms
#define OFF_W1B      7899536    // bf16 [896][20000]
#define OFF_RNNB     16859536   // bf16 [512][20000]
#define OFF_EMWB     21979536   // bf16 [256][20000]
#define OFF_LOGITH   7899536    // f16 E [2500][20000]
// total ws: 24,539,536 floats = 98.2 MB

typedef _Float16 h2v __attribute__((ext_vector_type(2)));
typedef __bf16 bf16x8 __attribute__((ext_vector_type(8)));
typedef float f32x4 __attribute__((ext_vector_type(4)));

__device__ inline float dot2u(u32 a, u32 b, float c){
  h2v ha = __builtin_bit_cast(h2v, a), hb = __builtin_bit_cast(h2v, b);
#if __has_builtin(__builtin_amdgcn_fdot2)
  return __builtin_amdgcn_fdot2(ha, hb, c, false);
#else
  return c + (float)ha.x*(float)hb.x + (float)ha.y*(float)hb.y;
#endif
}

__device__ inline u32 packh2(float lo, float hi){
  h2v h; h.x = (_Float16)lo; h.y = (_Float16)hi;
  return __builtin_bit_cast(u32, h);
}

__device__ inline ushort_t f2bf(float f){
  u32 u = __builtin_bit_cast(u32, f);
  u = (u + 0x7FFFu + ((u >> 16) & 1u)) >> 16;
  return (ushort_t)u;
}

__device__ inline float fast_sig(float x){ return 1.f/(1.f + __expf(-x)); }
__device__ inline float fast_tanh(float x){ float e = __expf(2.f*x); return 1.f - 2.f/(e + 1.f); }

__device__ __forceinline__ void gl2lds16(const void* g, void* l){
  __builtin_amdgcn_global_load_lds((__attribute__((address_space(1))) void*)g,
                                   (__attribute__((address_space(3))) void*)l,
                                   16, 0, 0);
}

__device__ inline void blockReduceAdd(float v, float* red, float* target){
  int tid = threadIdx.x;
  red[tid] = v; __syncthreads();
  for (int o = blockDim.x >> 1; o > 0; o >>= 1){
    if (tid < o) red[tid] += red[tid + o];
    __syncthreads();
  }
  if (tid == 0) atomicAdd(target, red[0]);
}

// ---------------- prep: f16 packs, bias2, W1E compact, doc buckets ----------------
__global__ __launch_bounds__(256) void k_prep(
    const float* __restrict__ whh,
    const float* __restrict__ muEW, const float* __restrict__ lsEW,
    const float* __restrict__ bih, const float* __restrict__ bhh,
    const float* __restrict__ wih, const float* __restrict__ emapB,
    const float* __restrict__ W1, const int* __restrict__ times,
    float* __restrict__ W)
{
  int idx = blockIdx.x*256 + threadIdx.x;
  u32* whhH = (u32*)(W + OFF_WHH_H);
  u32* etaWH = (u32*)(W + OFF_ETAWH);
  float* bias2 = W + OFF_BIAS2;
  float* w1e = W + OFF_W1E;
  int* docCnt = (int*)(W + OFF_DOCCNT);
  int* docList = (int*)(W + OFF_DOCLIST);
  if (idx < 80000){
    int j = idx/100; int i = idx - j*100;
    whhH[idx] = packh2(whh[j*200 + 2*i], whh[j*200 + 2*i + 1]);
  } else if (idx < 92500){
    int d = idx - 80000; int q = d/125; int i = d - q*125;
    const float* src = (q < 50) ? (muEW + q*250) : (lsEW + (q-50)*250);
    etaWH[d] = packh2(src[2*i], src[2*i+1]);
  } else if (idx < 93300){
    int j = idx - 92500;
    float acc = bih[j] + bhh[j];
    const float* wr = wih + (size_t)j*200;
    #pragma unroll 4
    for (int k = 0; k < 200; k++) acc += emapB[k]*wr[k];
    bias2[j] = acc;
  } else if (idx < 133300){
    int d = idx - 93300; int j = d/50; int k = d - j*50;
    w1e[d] = W1[(size_t)j*20050 + 20000 + k];
  } else if (idx < 133556){
    int b = idx - 133300; int t = times[b];
    int pos = atomicAdd(&docCnt[t], 1);
    docList[t*256 + pos] = b;
  }
}

// ---------------- generic fp32 -> bf16 padded row-major convert ----------------
__global__ __launch_bounds__(256) void k_conv(const float* __restrict__ src, int ldsrc,
                                              int Mreal, int Kused,
                                              ushort_t* __restrict__ dst, int Mp, int Kp)
{
  int idx = blockIdx.x*256 + threadIdx.x;
  int kb = Kp >> 3;
  if (idx >= Mp*kb) return;
  int row = idx / kb, c = (idx - row*kb) << 3;
  ushort_t out[8];
  #pragma unroll
  for (int j = 0; j < 8; j++){
    float v = 0.f;
    int k = c + j;
    if (row < Mreal && k < Kused) v = src[(size_t)row*ldsrc + k];
    out[j] = f2bf(v);
  }
  *(uint4*)(dst + (size_t)row*Kp + c) = *(uint4*)out;
}

// ---------------- alphas permute + bf16 pad ----------------
__global__ __launch_bounds__(256) void k_conva(const float* __restrict__ muq, ushort_t* __restrict__ dst)
{
  int idx = blockIdx.x*256 + threadIdx.x;
  if (idx >= 2560*40) return;
  int row = idx / 40, c = (idx - row*40) << 3;
  ushort_t out[8];
  const float* src = nullptr;
  if (row < 2500){ int t = row/50, k = row - t*50; src = muq + (size_t)k*15000 + t*300; }
  #pragma unroll
  for (int j = 0; j < 8; j++){
    int r = c + j;
    float v = (src && r < 300) ? src[r] : 0.f;
    out[j] = f2bf(v);
  }
  *(uint4*)(dst + (size_t)row*320 + c) = *(uint4*)out;
}

// ---------------- bf16 MFMA NT GEMM: C[M,N] = A[M,K] . B[N,K]^T ----------------
// MODE 0: atomic f32; MODE 2: f32 store + col-bias; MODE 3: f16 store of exp(v) + atomic row-sum Z
// block order: kIdx fastest, then mIdx (m-fast for B-tile L2 reuse), then nIdx.
template<int MODE>
__global__ __launch_bounds__(256) void mfma_nt(
    const ushort_t* __restrict__ A, int lda,
    const ushort_t* __restrict__ B, int ldb,
    float* __restrict__ C, _Float16* __restrict__ Ch, int ldc,
    const float* __restrict__ nBias,
    int M, int N, int mT, int kS, int chunks)
{
  __shared__ __align__(16) ushort_t As[128*32];
  __shared__ __align__(16) ushort_t Bs[128*32];
  int bid = blockIdx.x;
  int kIdx = bid % kS; int rest = bid / kS;
  int mIdx = rest % mT; int nIdx = rest / mT;
  int tid = threadIdx.x;
  int w = tid >> 6, l = tid & 63;
  int c0 = (int)(((long long)chunks * kIdx) / kS);
  int c1 = (int)(((long long)chunks * (kIdx+1)) / kS);
  int r0 = w*32;
  const ushort_t* ga0 = A + (size_t)(mIdx*128 + r0      + (l>>2))*lda + (l&3)*8;
  const ushort_t* ga1 = A + (size_t)(mIdx*128 + r0 + 16 + (l>>2))*lda + (l&3)*8;
  const ushort_t* gb0 = B + (size_t)(nIdx*128 + r0      + (l>>2))*ldb + (l&3)*8;
  const ushort_t* gb1 = B + (size_t)(nIdx*128 + r0 + 16 + (l>>2))*ldb + (l&3)*8;
  ushort_t* la = As + r0*32;
  ushort_t* lb = Bs + r0*32;
  int wr = (w >> 1)*64, wc = (w & 1)*64;
  int lr = l & 15, lq = l >> 4;
  f32x4 acc[4][4];
  #pragma unroll
  for (int i = 0; i < 4; i++)
    #pragma unroll
    for (int j = 0; j < 4; j++)
      acc[i][j] = (f32x4)0.f;

  for (int c = c0; c < c1; c++){
    size_t ko = (size_t)c * 32;
    gl2lds16(ga0 + ko, la);
    gl2lds16(ga1 + ko, la + 512);
    gl2lds16(gb0 + ko, lb);
    gl2lds16(gb1 + ko, lb + 512);
    __syncthreads();
    bf16x8 av[4], bv[4];
    #pragma unroll
    for (int i = 0; i < 4; i++)
      av[i] = *(const bf16x8*)(As + (wr + i*16 + lr)*32 + lq*8);
    #pragma unroll
    for (int j = 0; j < 4; j++)
      bv[j] = *(const bf16x8*)(Bs + (wc + j*16 + lr)*32 + lq*8);
    #pragma unroll
    for (int i = 0; i < 4; i++)
      #pragma unroll
      for (int j = 0; j < 4; j++)
        acc[i][j] = __builtin_amdgcn_mfma_f32_16x16x32_bf16(av[i], bv[j], acc[i][j], 0, 0, 0);
    __syncthreads();
  }
  if (MODE == 3){
    // store exp(v) as f16, accumulate row-sums into Z (=C)
    float* Z = C;
    #pragma unroll
    for (int i = 0; i < 4; i++){
      #pragma unroll
      for (int r = 0; r < 4; r++){
        int row = mIdx*128 + wr + i*16 + lq*4 + r;
        float p = 0.f;
        if (row < M){
          #pragma unroll
          for (int j = 0; j < 4; j++){
            int col = nIdx*128 + wc + j*16 + lr;
            if (col < N){
              float e = __expf(acc[i][j][r]);
              Ch[(size_t)row*ldc + col] = (_Float16)e;
              p += e;
            }
          }
        }
        p += __shfl_xor(p, 1, 16);
        p += __shfl_xor(p, 2, 16);
        p += __shfl_xor(p, 4, 16);
        p += __shfl_xor(p, 8, 16);
        if (lr == 0 && row < M) atomicAdd(&Z[row], p);
      }
    }
  } else {
    #pragma unroll
    for (int i = 0; i < 4; i++){
      #pragma unroll
      for (int r = 0; r < 4; r++){
        int row = mIdx*128 + wr + i*16 + lq*4 + r;
        if (row >= M) continue;
        #pragma unroll
        for (int j = 0; j < 4; j++){
          int col = nIdx*128 + wc + j*16 + lr;
          if (col >= N) continue;
          float v = acc[i][j][r];
          if (MODE == 0)      atomicAdd(&C[(size_t)row*ldc + col], v);
          else                C[(size_t)row*ldc + col] = v + nBias[col];
        }
      }
    }
  }
}

// ---------------- kl_alpha ----------------
__global__ __launch_bounds__(256) void k_klalpha(const float* __restrict__ muq,
                                                 const float* __restrict__ lsq,
                                                 float* __restrict__ W)
{
  __shared__ float red[256];
  const float inv_dl = 1.f/(0.005f + 1e-6f);
  const float logdl = -5.2983173665480363f;
  float local = 0.f;
  for (int idx = blockIdx.x*256 + threadIdx.x; idx < 750000; idx += gridDim.x*256){
    int rem = idx % 15000; int t = rem / 300;
    float ls = lsq[idx]; float mu = muq[idx];
    if (t == 0){
      local += 0.5f*((__expf(ls) + mu*mu)/(1.f + 1e-6f) - 1.f - ls);
    } else {
      float d = mu - muq[idx - 300];
      local += 0.5f*((__expf(ls) + d*d)*inv_dl - 1.f + logdl - ls);
    }
  }
  blockReduceAdd(local, red, W + OFF_SCAL + 1);
}

// ---------------- fused LSTM + eta recurrence, one block per source ----------------
// launch_bounds(512,2): 256-VGPR budget so wreg[200] stays in registers (no spill).
// All dot products use 4 independent accumulators (short dep chains).
__global__ __launch_bounds__(512, 2) void k_lstm(
    const float* __restrict__ xw, const u32* __restrict__ whhH, const u32* __restrict__ etaWH,
    const float* __restrict__ muEB, const float* __restrict__ lsEB,
    float* __restrict__ etas, float* __restrict__ W)
{
  int s = blockIdx.x; int tid = threadIdx.x;
  __shared__ uint4 hp4[32];      // f16 pairs: dwords [0..99]=h(200), [100..124]=eta_prev(50), rest 0
  __shared__ float zbuf[800];
  __shared__ float red[512];
  u32 wreg[200];
  #pragma unroll
  for (int i = 0; i < 200; i++) wreg[i] = 0u;
  if (tid < 400){
    const u32* ra = whhH + tid*100;
    const u32* rb = whhH + (tid + 400)*100;
    #pragma unroll
    for (int i = 0; i < 100; i++){ wreg[i] = ra[i]; wreg[100+i] = rb[i]; }
  } else if (tid < 500){
    int q = tid - 400;
    const u32* re = etaWH + q*125;
    #pragma unroll
    for (int i = 0; i < 125; i++) wreg[i] = re[i];
  }
  float ebias = 0.f;
  if (tid >= 400 && tid < 500){
    int q = tid - 400;
    ebias = (q < 50) ? muEB[q] : lsEB[q - 50];
  }
  float creg = 0.f, muPrev = 0.f, klLocal = 0.f;
  if (tid < 32){ uint4 z; z.x=z.y=z.z=z.w=0u; hp4[tid] = z; }
  __syncthreads();
  const float inv_dl = 1.f/(0.005f + 1e-6f);
  const float logdl = -5.2983173665480363f;
  _Float16* hview = (_Float16*)hp4;

  for (int t = 0; t < NT_T; t++){
    if (tid < 400){
      float a0=0.f,a1=0.f,a2=0.f,a3=0.f,b0=0.f,b1=0.f,b2=0.f,b3=0.f;
      #pragma unroll
      for (int i4 = 0; i4 < 25; i4++){
        uint4 h = hp4[i4];
        a0 = dot2u(wreg[i4*4+0], h.x, a0);
        a1 = dot2u(wreg[i4*4+1], h.y, a1);
        a2 = dot2u(wreg[i4*4+2], h.z, a2);
        a3 = dot2u(wreg[i4*4+3], h.w, a3);
        b0 = dot2u(wreg[100+i4*4+0], h.x, b0);
        b1 = dot2u(wreg[100+i4*4+1], h.y, b1);
        b2 = dot2u(wreg[100+i4*4+2], h.z, b2);
        b3 = dot2u(wreg[100+i4*4+3], h.w, b3);
      }
      const float* xr = xw + (size_t)(s*50 + t)*800;
      zbuf[tid]       = ((a0+a1)+(a2+a3)) + xr[tid];
      zbuf[tid + 400] = ((b0+b1)+(b2+b3)) + xr[tid + 400];
    }
    __syncthreads();  // B1: zbuf ready
    if (tid < 200){
      float zi = zbuf[tid], zf = zbuf[200+tid], zg = zbuf[400+tid], zo = zbuf[600+tid];
      float ig = fast_sig(zi);
      float fg = fast_sig(zf);
      float gg = fast_tanh(zg);
      float og = fast_sig(zo);
      creg = fg*creg + ig*gg;
      float hv = og*fast_tanh(creg);
      hview[tid] = (_Float16)hv;
    }
    __syncthreads();  // B2: h ready
    float eacc = 0.f;
    bool isEta = (tid >= 400 && tid < 500);
    if (isEta){
      float e0=ebias, e1=0.f, e2=0.f, e3=0.f;
      #pragma unroll
      for (int i4 = 0; i4 < 32; i4++){
        uint4 h = hp4[i4];
        e0 = dot2u(wreg[i4*4+0], h.x, e0);
        e1 = dot2u(wreg[i4*4+1], h.y, e1);
        e2 = dot2u(wreg[i4*4+2], h.z, e2);
        e3 = dot2u(wreg[i4*4+3], h.w, e3);
      }
      eacc = (e0+e1)+(e2+e3);
    }
    __syncthreads();  // B3: protect eta_prev region reads vs writes below
    if (isEta){
      int q = tid - 400;
      if (q < 50){
        float mu = eacc;
        etas[(size_t)(s*50 + t)*50 + q] = mu;
        if (t == 0) klLocal += 0.5f*mu*mu/(1.f + 1e-6f);
        else { float d = mu - muPrev; klLocal += 0.5f*d*d*inv_dl; }
        muPrev = mu;
        hview[200 + q] = (_Float16)mu;
      } else {
        float ls = eacc;
        if (t == 0) klLocal += 0.5f*(__expf(ls)/(1.f + 1e-6f) - 1.f - ls);
        else {
          ls = fminf(fmaxf(ls, -10.f), 10.f);
          klLocal += 0.5f*(__expf(ls)*inv_dl - 1.f + logdl - ls);
        }
      }
    }
  }
  __syncthreads();
  blockReduceAdd(klLocal, red, W + OFF_SCAL + 2);
}

// ---------------- h1 = relu(hpre + b1 + eta_std @ W1E^T) -> bf16 ----------------
__global__ __launch_bounds__(256) void k_h1(
    const float* __restrict__ hpre, const float* __restrict__ b1, const float* __restrict__ w1e,
    const float* __restrict__ etas, const int* __restrict__ times, const int* __restrict__ srcs,
    ushort_t* __restrict__ h1B)
{
  int b = blockIdx.x, tid = threadIdx.x;
  __shared__ float et[50];
  int tb = times[b], sb = srcs[b];
  if (tid < 50) et[tid] = etas[(size_t)(sb*50 + tb)*50 + tid];
  __syncthreads();
  for (int j = tid; j < 800; j += 256){
    float acc = hpre[(size_t)b*800 + j] + b1[j];
    const float* wrow = w1e + (size_t)j*50;
    #pragma unroll
    for (int k = 0; k < 50; k++) acc += et[k]*wrow[k];
    h1B[(size_t)b*800 + j] = f2bf(fmaxf(acc, 0.f));
  }
}

// ---------------- theta head (h2pre + b2, relu folded; wcoef = theta/Z) ----------------
__global__ __launch_bounds__(256) void k_thfin(
    const float* __restrict__ h2g, const float* __restrict__ b2, const float* __restrict__ etas,
    const int* __restrict__ times, const int* __restrict__ srcs,
    const float* __restrict__ muW, const float* __restrict__ muB,
    const float* __restrict__ lsW, const float* __restrict__ lsB,
    const float* __restrict__ clsW, const float* __restrict__ clsB,
    const float* __restrict__ Zrow, float* __restrict__ wcoef, float* __restrict__ W)
{
  int b = blockIdx.x, tid = threadIdx.x;
  __shared__ float h2s[800], mu[50], lsv[50], et[50], th[50], lg[10], red[64], shm[2];
  for (int j = tid; j < 800; j += 256) h2s[j] = fmaxf(h2g[(size_t)b*800 + j] + b2[j], 0.f);
  int tb = times[b], sb = srcs[b];
  if (tid < 50) et[tid] = etas[(size_t)(sb*50 + tb)*50 + tid];
  __syncthreads();
  if (tid < 100){
    int q = (tid < 50) ? tid : tid - 50;
    const float* w = (tid < 50) ? (muW + (size_t)q*800) : (lsW + (size_t)q*800);
    float acc = (tid < 50) ? muB[q] : lsB[q];
    #pragma unroll 8
    for (int j = 0; j < 800; j++) acc += h2s[j]*w[j];
    if (tid < 50) mu[q] = acc;
    else lsv[q] = fminf(fmaxf(acc, -10.f), 10.f);
  }
  __syncthreads();
  if (tid == 0){ float m = -1e30f; for (int k = 0; k < 50; k++) m = fmaxf(m, mu[k]); shm[0] = m; }
  __syncthreads();
  if (tid < 50) th[tid] = __expf(mu[tid] - shm[0]);
  __syncthreads();
  if (tid == 0){ float z = 0.f; for (int k = 0; k < 50; k++) z += th[k]; shm[1] = z; }
  __syncthreads();
  if (tid < 64) red[tid] = 0.f;
  if (tid < 50){
    float t_ = th[tid]/shm[1]; th[tid] = t_;
    wcoef[(size_t)b*50 + tid] = t_/Zrow[tb*50 + tid];
    float d = mu[tid] - et[tid];
    red[tid] = 0.5f*((__expf(lsv[tid]) + d*d)/(1.f + 1e-6f) - 1.f - lsv[tid]);
  }
  __syncthreads();
  if (tid < 10){
    float a = clsB[tid];
    #pragma unroll
    for (int k = 0; k < 50; k++) a += th[k]*clsW[tid*50 + k];
    lg[tid] = a;
  }
  __syncthreads();
  if (tid == 0){
    float m = -1e30f; for (int i = 0; i < 10; i++) m = fmaxf(m, lg[i]);
    float z = 0.f; for (int i = 0; i < 10; i++) z += __expf(lg[i] - m);
    float lse = m + __logf(z);
    atomicAdd(W + OFF_SCAL + 4, lse - lg[sb]);
    float ssum = 0.f; for (int i = 0; i < 50; i++) ssum += red[i];
    atomicAdd(W + OFF_SCAL + 3, ssum);
  }
}

// ---------------- nll: E already exponentiated ----------------
__global__ __launch_bounds__(256) void k_nll(
    const _Float16* __restrict__ E, const float* __restrict__ wcoef,
    const float* __restrict__ bows, float* __restrict__ W)
{
  int t = blockIdx.x/10, vc = blockIdx.x%10;
  int v0 = vc*2000;
  int tid = threadIdx.x;
  const int* docCnt = (const int*)(W + OFF_DOCCNT);
  const int* docList = (const int*)(W + OFF_DOCLIST);
  __shared__ float wch[64*50];
  __shared__ int ids[64];
  __shared__ float red[256];
  int nd = docCnt[t];
  float acc = 0.f;
  for (int d0 = 0; d0 < nd; d0 += 64){
    int ndc = min(64, nd - d0);
    __syncthreads();
    for (int i = tid; i < ndc*50; i += 256){
      int d = i/50, k = i - d*50;
      int bb = docList[t*256 + d0 + d];
      if (k == 0) ids[d] = bb;
      wch[i] = wcoef[(size_t)bb*50 + k];
    }
    __syncthreads();
    for (int v = v0 + tid; v < v0 + 2000; v += 256){
      float e[50];
      #pragma unroll
      for (int k = 0; k < 50; k++)
        e[k] = (float)E[(size_t)(t*50 + k)*NVOC + v];
      for (int d = 0; d < ndc; d++){
        float s = 0.f;
        #pragma unroll
        for (int k = 0; k < 50; k++) s += wch[d*50 + k]*e[k];
        acc += bows[(size_t)ids[d]*NVOC + v]*__logf(s);
      }
    }
  }
  __syncthreads();
  blockReduceAdd(acc, red, W + OFF_SCAL + 0);
}

// ---------------- finalize ----------------
__global__ void k_final(const float* __restrict__ W, const int* __restrict__ ndocs, float* __restrict__ out)
{
  if (blockIdx.x == 0 && threadIdx.x == 0){
    float coeff = (float)ndocs[0] / 256.f;
    const float* scal = W + OFF_SCAL;
    float nll  = -scal[0]*coeff;
    float kla  = scal[1];
    float kle  = scal[2];
    float klth = scal[3]*coeff;
    float pred = scal[4]*coeff;
    out[0] = nll + kla + kle + klth + pred;
    out[1] = nll; out[2] = kla; out[3] = kle; out[4] = klth; out[5] = pred;
  }
}

extern "C" void kernel_launch(void* const* d_in, const int* in_sizes, int n_in,
                              void* d_out, int out_size, void* d_ws, size_t ws_size,
                              hipStream_t stream)
{
  (void)in_sizes; (void)n_in; (void)out_size; (void)ws_size;
  const float* bows  = (const float*)d_in[1];
  const float* nb    = (const float*)d_in[2];
  const int*   times = (const int*)d_in[3];
  const int*   srcs  = (const int*)d_in[4];
  const float* rnn   = (const float*)d_in[5];
  const int*   ndocs = (const int*)d_in[6];
  const float* muq   = (const float*)d_in[7];
  const float* lsq   = (const float*)d_in[8];
  const float* rho   = (const float*)d_in[9];
  const float* W1    = (const float*)d_in[10];
  const float* b1    = (const float*)d_in[11];
  const float* W2    = (const float*)d_in[12];
  const float* b2    = (const float*)d_in[13];
  const float* muthW = (const float*)d_in[14];
  const float* muthB = (const float*)d_in[15];
  const float* lsthW = (const float*)d_in[16];
  const float* lsthB = (const float*)d_in[17];
  const float* emapW = (const float*)d_in[18];
  const float* emapB = (const float*)d_in[19];
  const float* wih   = (const float*)d_in[20];
  const float* whh   = (const float*)d_in[21];
  const float* bih   = (const float*)d_in[22];
  const float* bhh   = (const float*)d_in[23];
  const float* muEW  = (const float*)d_in[24];
  const float* muEB  = (const float*)d_in[25];
  const float* lsEW  = (const float*)d_in[26];
  const float* lsEB  = (const float*)d_in[27];
  const float* clsW  = (const float*)d_in[28];
  const float* clsB  = (const float*)d_in[29];

  float* W = (float*)d_ws;
  ushort_t* alphaB = (ushort_t*)(W + OFF_ALPHAB);
  ushort_t* rhoB   = (ushort_t*)(W + OFF_RHOB);
  ushort_t* nbB    = (ushort_t*)(W + OFF_NBB);
  ushort_t* w1B    = (ushort_t*)(W + OFF_W1B);
  ushort_t* rnnB   = (ushort_t*)(W + OFF_RNNB);
  ushort_t* emwB   = (ushort_t*)(W + OFF_EMWB);
  ushort_t* wihB   = (ushort_t*)(W + OFF_WIHB);
  ushort_t* w2B    = (ushort_t*)(W + OFF_W2B);
  ushort_t* mapB   = (ushort_t*)(W + OFF_MAPB);
  ushort_t* h1B    = (ushort_t*)(W + OFF_H1B);
  _Float16* Ehalf  = (_Float16*)(W + OFF_LOGITH);

  hipMemsetAsync(d_ws, 0, MEMSET_BYTES, stream);

  k_prep<<<522, 256, 0, stream>>>(whh, muEW, lsEW, bih, bhh, wih, emapB, W1, times, W);

  // bf16 conversions
  k_conva<<<400, 256, 0, stream>>>(muq, alphaB);
  k_conv<<<3140, 256, 0, stream>>>(rho, 300, 20000, 300, rhoB, 20096, 320);
  k_conv<<<2500, 256, 0, stream>>>(nb, 20000, 256, 20000, nbB, 256, 20000);
  k_conv<<<8750, 256, 0, stream>>>(W1, 20050, 800, 20000, w1B, 896, 20000);
  k_conv<<<5000, 256, 0, stream>>>(rnn, 20000, 500, 20000, rnnB, 512, 20000);
  k_conv<<<2500, 256, 0, stream>>>(emapW, 20000, 200, 20000, emwB, 256, 20000);
  k_conv<<<98, 256, 0, stream>>>(wih, 200, 800, 200, wihB, 896, 224);
  k_conv<<<350, 256, 0, stream>>>(W2, 800, 800, 800, w2B, 896, 800);

  // mapped = rnn @ eta_map_W^T  M=500 N=200 K=20000  (split-K atomic)
  mfma_nt<0><<<4*2*32, 256, 0, stream>>>(
      rnnB, 20000, emwB, 20000, W + OFF_MAPPED, nullptr, 200, nullptr,
      500, 200, 4, 32, 625);

  // hpre = nb @ W1[:, :V]^T  M=256 N=800 K=20000  (split-K atomic)
  mfma_nt<0><<<2*7*20, 256, 0, stream>>>(
      nbB, 20000, w1B, 20000, W + OFF_HPRE, nullptr, 800, nullptr,
      256, 800, 2, 20, 625);

  // E = exp(alphasT @ rho^T) -> f16 + row-sums Z   M=2500 N=20000 K=320
  // (overwrites w1B/rnnB/emwB region — must run after mapped & hpre gemms)
  mfma_nt<3><<<20*157, 256, 0, stream>>>(
      alphaB, 320, rhoB, 320, W + OFF_Z, Ehalf, 20000, nullptr,
      2500, 20000, 20, 1, 10);

  // mapped -> bf16 [512][224]
  k_conv<<<56, 256, 0, stream>>>(W + OFF_MAPPED, 200, 500, 200, mapB, 512, 224);

  // xw = mapped @ wih^T + bias2  M=500 N=800 K=224
  mfma_nt<2><<<4*7, 256, 0, stream>>>(
      mapB, 224, wihB, 224, W + OFF_XW, nullptr, 800, W + OFF_BIAS2,
      500, 800, 4, 1, 7);

  k_klalpha<<<1024, 256, 0, stream>>>(muq, lsq, W);

  k_lstm<<<NSRC, 512, 0, stream>>>(W + OFF_XW, (const u32*)(W + OFF_WHH_H),
                                   (const u32*)(W + OFF_ETAWH), muEB, lsEB,
                                   W + OFF_ETAS, W);

  k_h1<<<256, 256, 0, stream>>>(W + OFF_HPRE, b1, W + OFF_W1E, W + OFF_ETAS, times, srcs, h1B);

  // h2pre = h1 @ W2^T  M=256 N=800 K=800  (split-K atomic; b2+relu folded into k_thfin)
  mfma_nt<0><<<2*7*2, 256, 0, stream>>>(
      h1B, 800, w2B, 800, W + OFF_H2, nullptr, 800, nullptr,
      256, 800, 2, 2, 25);

  k_thfin<<<256, 256, 0, stream>>>(W + OFF_H2, b2, W + OFF_ETAS, times, srcs,
                                   muthW, muthB, lsthW, lsthB, clsW, clsB,
                                   W + OFF_Z, W + OFF_WCOEF, W);

  k_nll<<<500, 256, 0, stream>>>(Ehalf, W + OFF_WCOEF, bows, W);

  k_final<<<1, 64, 0, stream>>>(W, ndocs, (float*)d_out);
}

// Round 5
// 711.967 us; speedup vs baseline: 3.2737x; 1.0308x over previous
//
#include <hip/hip_runtime.h>

typedef unsigned int u32;
typedef unsigned short ushort_t;

// problem dims
#define NTOP 50
#define NT_T 50
#define NRHO 300
#define NVOC 20000
#define NTH 800
#define NEH 200
#define NSRC 10
#define NBAT 256

// ws offsets (float units), all 8-float (32B) aligned
#define OFF_SCAL     0          // 5 accumulators
#define OFF_MAPPED   16         // 500*200 fp32 (atomic)
#define OFF_HPRE     100016     // 256*800 fp32 (atomic)
#define OFF_H2       304816     // 256*800 fp32 (atomic)
#define OFF_Z        509616     // 2500 fp32 (atomic row-sums of E)
#define OFF_DOCCNT   512120     // 50 ints
#define OFF_DOCLIST  512176     // 50*256 ints
#define MEMSET_BYTES ((size_t)524976 * 4)
#define OFF_XW       524976     // 500*800 fp32
#define OFF_BIAS2    924976     // 800
#define OFF_ETAS     925776     // 10*50*50
#define OFF_WCOEF    950776     // 256*50
#define OFF_W1E      963576     // 800*50 compact W1[:,V:]
#define OFF_WHH_H    1003576    // 80000 u32 (f16 pairs) rows of 100
#define OFF_ETAWH    1083576    // 12800 u32 (f16 pairs) rows of 128 (125 used + 3 zero)
#define OFF_H1B      1096376    // bf16 [256][800]
#define OFF_MAPB     1198776    // bf16 [512][224]
#define OFF_WIHB     1256120    // bf16 [896][224]
#define OFF_W2B      1356472    // bf16 [896][800]
#define OFF_ALPHAB   1714872    // bf16 [2560][320]
#define OFF_RHOB     2124472    // bf16 [20096][320]
#define OFF_NBB      5339832    // bf16 [256][20000]
// union: {W1B, RNNB, EMWB} reused by E (LOGITH) after mapped/hpre gemms
#define OFF_W1B      7899832    // bf16 [896][20000]
#define OFF_RNNB     16859832   // bf16 [512][20000]
#define OFF_EMWB     21979832   // bf16 [256][20000]
#define OFF_LOGITH   7899832    // f16 E [2500][20000]
// total ws: 24,539,832 floats = 98.16 MB

typedef _Float16 h2v __attribute__((ext_vector_type(2)));
typedef __bf16 bf16x8 __attribute__((ext_vector_type(8)));
typedef float f32x4 __attribute__((ext_vector_type(4)));

#define REP25(M) M(0) M(1) M(2) M(3) M(4) M(5) M(6) M(7) M(8) M(9) M(10) M(11) M(12) \
                 M(13) M(14) M(15) M(16) M(17) M(18) M(19) M(20) M(21) M(22) M(23) M(24)
#define REP7(M) M(0) M(1) M(2) M(3) M(4) M(5) M(6)

__device__ inline float dot2u(u32 a, u32 b, float c){
  h2v ha = __builtin_bit_cast(h2v, a), hb = __builtin_bit_cast(h2v, b);
#if __has_builtin(__builtin_amdgcn_fdot2)
  return __builtin_amdgcn_fdot2(ha, hb, c, false);
#else
  return c + (float)ha.x*(float)hb.x + (float)ha.y*(float)hb.y;
#endif
}

__device__ inline u32 packh2(float lo, float hi){
  h2v h; h.x = (_Float16)lo; h.y = (_Float16)hi;
  return __builtin_bit_cast(u32, h);
}

__device__ inline ushort_t f2bf(float f){
  u32 u = __builtin_bit_cast(u32, f);
  u = (u + 0x7FFFu + ((u >> 16) & 1u)) >> 16;
  return (ushort_t)u;
}

__device__ inline float fast_sig(float x){ return 1.f/(1.f + __expf(-x)); }
__device__ inline float fast_tanh(float x){ float e = __expf(2.f*x); return 1.f - 2.f/(e + 1.f); }

__device__ __forceinline__ void gl2lds16(const void* g, void* l){
  __builtin_amdgcn_global_load_lds((__attribute__((address_space(1))) void*)g,
                                   (__attribute__((address_space(3))) void*)l,
                                   16, 0, 0);
}

__device__ inline void blockReduceAdd(float v, float* red, float* target){
  int tid = threadIdx.x;
  red[tid] = v; __syncthreads();
  for (int o = blockDim.x >> 1; o > 0; o >>= 1){
    if (tid < o) red[tid] += red[tid + o];
    __syncthreads();
  }
  if (tid == 0) atomicAdd(target, red[0]);
}

// ---------------- device helper: fp32 -> bf16 padded row-major convert ----------------
__device__ inline void conv_seg(const float* __restrict__ src, int ldsrc,
                                int Mreal, int Kused,
                                ushort_t* __restrict__ dst, int Kp, int idx)
{
  int kb = Kp >> 3;
  int row = idx / kb, c = (idx - row*kb) << 3;
  ushort_t out[8];
  #pragma unroll
  for (int j = 0; j < 8; j++){
    float v = 0.f;
    int k = c + j;
    if (row < Mreal && k < Kused) v = src[(size_t)row*ldsrc + k];
    out[j] = f2bf(v);
  }
  *(uint4*)(dst + (size_t)row*Kp + c) = *(uint4*)out;
}

// ---------------- mega prep/convert/klalpha kernel (one launch) ----------------
// segments by blockIdx: [0,523) prep; [523,923) conva; [923,4063) rho; [4063,6563) nb;
// [6563,15313) W1; [15313,20313) rnn; [20313,22813) emw; [22813,22911) wih;
// [22911,23261) W2; [23261,24285) klalpha
__global__ __launch_bounds__(256) void k_mega(
    const float* __restrict__ whh,
    const float* __restrict__ muEW, const float* __restrict__ lsEW,
    const float* __restrict__ bih, const float* __restrict__ bhh,
    const float* __restrict__ wih, const float* __restrict__ emapB,
    const float* __restrict__ W1, const int* __restrict__ times,
    const float* __restrict__ muq, const float* __restrict__ lsq,
    const float* __restrict__ rho, const float* __restrict__ nb,
    const float* __restrict__ rnn, const float* __restrict__ emapW,
    const float* __restrict__ W2f, float* __restrict__ W)
{
  int b = blockIdx.x, tid = threadIdx.x;
  __shared__ float red[256];
  if (b < 523){
    int idx = b*256 + tid;
    u32* whhH = (u32*)(W + OFF_WHH_H);
    u32* etaWH = (u32*)(W + OFF_ETAWH);
    if (idx < 80000){
      int j = idx/100; int i = idx - j*100;
      whhH[idx] = packh2(whh[j*200 + 2*i], whh[j*200 + 2*i + 1]);
    } else if (idx < 92800){
      int d = idx - 80000; int q = d >> 7; int i = d & 127;
      u32 v = 0u;
      if (i < 125){
        const float* src = (q < 50) ? (muEW + q*250) : (lsEW + (q-50)*250);
        v = packh2(src[2*i], src[2*i+1]);
      }
      etaWH[d] = v;
    } else if (idx < 93600){
      int j = idx - 92800;
      float acc = bih[j] + bhh[j];
      const float* wr = wih + (size_t)j*200;
      #pragma unroll 4
      for (int k = 0; k < 200; k++) acc += emapB[k]*wr[k];
      W[OFF_BIAS2 + j] = acc;
    } else if (idx < 133600){
      int d = idx - 93600; int j = d/50; int k = d - j*50;
      W[OFF_W1E + d] = W1[(size_t)j*20050 + 20000 + k];
    } else if (idx < 133856){
      int bb = idx - 133600; int t = times[bb];
      int* docCnt = (int*)(W + OFF_DOCCNT);
      int* docList = (int*)(W + OFF_DOCLIST);
      int pos = atomicAdd(&docCnt[t], 1);
      docList[t*256 + pos] = bb;
    }
  } else if (b < 923){
    // alphas permute+pad: dst[t*50+k][r] = muq[k][t][r]
    int idx = (b-523)*256 + tid;
    int row = idx / 40, c = (idx - row*40) << 3;
    ushort_t out[8];
    const float* src = nullptr;
    if (row < 2500){ int t = row/50, k = row - t*50; src = muq + (size_t)k*15000 + t*300; }
    #pragma unroll
    for (int j = 0; j < 8; j++){
      int r = c + j;
      float v = (src && r < 300) ? src[r] : 0.f;
      out[j] = f2bf(v);
    }
    *(uint4*)((ushort_t*)(W + OFF_ALPHAB) + (size_t)row*320 + c) = *(uint4*)out;
  } else if (b < 4063){
    conv_seg(rho, 300, 20000, 300, (ushort_t*)(W + OFF_RHOB), 320, (b-923)*256 + tid);
  } else if (b < 6563){
    conv_seg(nb, 20000, 256, 20000, (ushort_t*)(W + OFF_NBB), 20000, (b-4063)*256 + tid);
  } else if (b < 15313){
    conv_seg(W1, 20050, 800, 20000, (ushort_t*)(W + OFF_W1B), 20000, (b-6563)*256 + tid);
  } else if (b < 20313){
    conv_seg(rnn, 20000, 500, 20000, (ushort_t*)(W + OFF_RNNB), 20000, (b-15313)*256 + tid);
  } else if (b < 22813){
    conv_seg(emapW, 20000, 200, 20000, (ushort_t*)(W + OFF_EMWB), 20000, (b-20313)*256 + tid);
  } else if (b < 22911){
    conv_seg(wih, 200, 800, 200, (ushort_t*)(W + OFF_WIHB), 224, (b-22813)*256 + tid);
  } else if (b < 23261){
    conv_seg(W2f, 800, 800, 800, (ushort_t*)(W + OFF_W2B), 800, (b-22911)*256 + tid);
  } else {
    // kl_alpha
    const float inv_dl = 1.f/(0.005f + 1e-6f);
    const float logdl = -5.2983173665480363f;
    float local = 0.f;
    for (int idx = (b-23261)*256 + tid; idx < 750000; idx += 1024*256){
      int rem = idx % 15000; int t = rem / 300;
      float ls = lsq[idx]; float mu = muq[idx];
      if (t == 0){
        local += 0.5f*((__expf(ls) + mu*mu)/(1.f + 1e-6f) - 1.f - ls);
      } else {
        float d = mu - muq[idx - 300];
        local += 0.5f*((__expf(ls) + d*d)*inv_dl - 1.f + logdl - ls);
      }
    }
    blockReduceAdd(local, red, W + OFF_SCAL + 1);
  }
}

// ---------------- small fp32 -> bf16 convert (for mapped, after its GEMM) ----------------
__global__ __launch_bounds__(256) void k_conv(const float* __restrict__ src, int ldsrc,
                                              int Mreal, int Kused,
                                              ushort_t* __restrict__ dst, int Mp, int Kp)
{
  int idx = blockIdx.x*256 + threadIdx.x;
  int kb = Kp >> 3;
  if (idx >= Mp*kb) return;
  conv_seg(src, ldsrc, Mreal, Kused, dst, Kp, idx);
}

// ---------------- bf16 MFMA NT GEMM: C[M,N] = A[M,K] . B[N,K]^T ----------------
// MODE 0: atomic f32; MODE 2: f32 store + col-bias; MODE 3: f16 store of exp(v) + atomic row-sum Z
// block order: kIdx fastest, then mIdx (m-fast for B-tile L2 reuse), then nIdx.
template<int MODE>
__global__ __launch_bounds__(256) void mfma_nt(
    const ushort_t* __restrict__ A, int lda,
    const ushort_t* __restrict__ B, int ldb,
    float* __restrict__ C, _Float16* __restrict__ Ch, int ldc,
    const float* __restrict__ nBias,
    int M, int N, int mT, int kS, int chunks)
{
  __shared__ __align__(16) ushort_t As[128*32];
  __shared__ __align__(16) ushort_t Bs[128*32];
  int bid = blockIdx.x;
  int kIdx = bid % kS; int rest = bid / kS;
  int mIdx = rest % mT; int nIdx = rest / mT;
  int tid = threadIdx.x;
  int w = tid >> 6, l = tid & 63;
  int c0 = (int)(((long long)chunks * kIdx) / kS);
  int c1 = (int)(((long long)chunks * (kIdx+1)) / kS);
  int r0 = w*32;
  const ushort_t* ga0 = A + (size_t)(mIdx*128 + r0      + (l>>2))*lda + (l&3)*8;
  const ushort_t* ga1 = A + (size_t)(mIdx*128 + r0 + 16 + (l>>2))*lda + (l&3)*8;
  const ushort_t* gb0 = B + (size_t)(nIdx*128 + r0      + (l>>2))*ldb + (l&3)*8;
  const ushort_t* gb1 = B + (size_t)(nIdx*128 + r0 + 16 + (l>>2))*ldb + (l&3)*8;
  ushort_t* la = As + r0*32;
  ushort_t* lb = Bs + r0*32;
  int wr = (w >> 1)*64, wc = (w & 1)*64;
  int lr = l & 15, lq = l >> 4;
  f32x4 acc[4][4];
  #pragma unroll
  for (int i = 0; i < 4; i++)
    #pragma unroll
    for (int j = 0; j < 4; j++)
      acc[i][j] = (f32x4)0.f;

  for (int c = c0; c < c1; c++){
    size_t ko = (size_t)c * 32;
    gl2lds16(ga0 + ko, la);
    gl2lds16(ga1 + ko, la + 512);
    gl2lds16(gb0 + ko, lb);
    gl2lds16(gb1 + ko, lb + 512);
    __syncthreads();
    bf16x8 av[4], bv[4];
    #pragma unroll
    for (int i = 0; i < 4; i++)
      av[i] = *(const bf16x8*)(As + (wr + i*16 + lr)*32 + lq*8);
    #pragma unroll
    for (int j = 0; j < 4; j++)
      bv[j] = *(const bf16x8*)(Bs + (wc + j*16 + lr)*32 + lq*8);
    #pragma unroll
    for (int i = 0; i < 4; i++)
      #pragma unroll
      for (int j = 0; j < 4; j++)
        acc[i][j] = __builtin_amdgcn_mfma_f32_16x16x32_bf16(av[i], bv[j], acc[i][j], 0, 0, 0);
    __syncthreads();
  }
  if (MODE == 3){
    float* Z = C;
    #pragma unroll
    for (int i = 0; i < 4; i++){
      #pragma unroll
      for (int r = 0; r < 4; r++){
        int row = mIdx*128 + wr + i*16 + lq*4 + r;
        float p = 0.f;
        if (row < M){
          #pragma unroll
          for (int j = 0; j < 4; j++){
            int col = nIdx*128 + wc + j*16 + lr;
            if (col < N){
              float e = __expf(acc[i][j][r]);
              Ch[(size_t)row*ldc + col] = (_Float16)e;
              p += e;
            }
          }
        }
        p += __shfl_xor(p, 1, 16);
        p += __shfl_xor(p, 2, 16);
        p += __shfl_xor(p, 4, 16);
        p += __shfl_xor(p, 8, 16);
        if (lr == 0 && row < M) atomicAdd(&Z[row], p);
      }
    }
  } else {
    #pragma unroll
    for (int i = 0; i < 4; i++){
      #pragma unroll
      for (int r = 0; r < 4; r++){
        int row = mIdx*128 + wr + i*16 + lq*4 + r;
        if (row >= M) continue;
        #pragma unroll
        for (int j = 0; j < 4; j++){
          int col = nIdx*128 + wc + j*16 + lr;
          if (col >= N) continue;
          float v = acc[i][j][r];
          if (MODE == 0)      atomicAdd(&C[(size_t)row*ldc + col], v);
          else                C[(size_t)row*ldc + col] = v + nBias[col];
        }
      }
    }
  }
}

// ---------------- fused LSTM + eta recurrence, one block per source ----------------
// Weights in 50 EXPLICIT uint4 registers per thread (arrays never promote on gfx950).
// tid<400: Whh rows (tid, tid+400) -> wa0..24 / wb0..24.
// tid in [400,500): eta row q overlaid on wa0..24 + wb0..6 (etaWH rows padded to 128 dwords).
// hp4[2] double buffer: h pairs dwords 0..99, eta_prev pairs dwords 100..124. 2 barriers/step.
__global__ __launch_bounds__(512, 2) void k_lstm(
    const float* __restrict__ xw, const u32* __restrict__ whhH, const uint4* __restrict__ etaW4,
    const float* __restrict__ muEB, const float* __restrict__ lsEB,
    float* __restrict__ etas, float* __restrict__ W)
{
  int s = blockIdx.x; int tid = threadIdx.x;
  __shared__ uint4 hp4[2][32];
  __shared__ float zbuf[800];
  __shared__ float red[512];
  uint4 z4; z4.x = z4.y = z4.z = z4.w = 0u;
#define DECLW(i) uint4 wa##i = z4, wb##i = z4;
  REP25(DECLW)
#undef DECLW
  float ebias = 0.f;
  if (tid < 400){
    const uint4* ra = (const uint4*)(whhH + tid*100);
    const uint4* rb = (const uint4*)(whhH + (tid + 400)*100);
#define LDW(i) wa##i = ra[i]; wb##i = rb[i];
    REP25(LDW)
#undef LDW
  } else if (tid < 500){
    int q = tid - 400;
    const uint4* re = etaW4 + q*32;
#define LDA(i) wa##i = re[i];
    REP25(LDA)
#undef LDA
#define LDB(i) wb##i = re[25+i];
    REP7(LDB)
#undef LDB
    ebias = (q < 50) ? muEB[q] : lsEB[q - 50];
  }
  float creg = 0.f, muPrev = 0.f, klLocal = 0.f;
  if (tid < 64) ((uint4*)hp4)[tid] = z4;
  __syncthreads();
  const float inv_dl = 1.f/(0.005f + 1e-6f);
  const float logdl = -5.2983173665480363f;

  for (int t = 0; t < NT_T; t++){
    const uint4* hc = hp4[t & 1];
    uint4* hn = hp4[(t + 1) & 1];
    if (tid < 400){
      float a0=0.f,a1=0.f,a2=0.f,a3=0.f,b0=0.f,b1=0.f,b2=0.f,b3=0.f;
#define DOT(i) { uint4 h = hc[i]; \
      a0 = dot2u(wa##i.x, h.x, a0); a1 = dot2u(wa##i.y, h.y, a1); \
      a2 = dot2u(wa##i.z, h.z, a2); a3 = dot2u(wa##i.w, h.w, a3); \
      b0 = dot2u(wb##i.x, h.x, b0); b1 = dot2u(wb##i.y, h.y, b1); \
      b2 = dot2u(wb##i.z, h.z, b2); b3 = dot2u(wb##i.w, h.w, b3); }
      REP25(DOT)
#undef DOT
      const float* xr = xw + (size_t)(s*50 + t)*800;
      zbuf[tid]       = ((a0+a1)+(a2+a3)) + xr[tid];
      zbuf[tid + 400] = ((b0+b1)+(b2+b3)) + xr[tid + 400];
    }
    __syncthreads();  // B1: zbuf ready
    if (tid < 200){
      float zi = zbuf[tid], zf = zbuf[200+tid], zg = zbuf[400+tid], zo = zbuf[600+tid];
      float ig = fast_sig(zi);
      float fg = fast_sig(zf);
      float gg = fast_tanh(zg);
      float og = fast_sig(zo);
      creg = fg*creg + ig*gg;
      float hv = og*fast_tanh(creg);
      ((_Float16*)hn)[tid] = (_Float16)hv;
    }
    __syncthreads();  // B2: h_t ready
    if (tid >= 400 && tid < 500){
      float e0 = ebias, e1 = 0.f, e2 = 0.f, e3 = 0.f;
#define DOTE(i) { uint4 h = hn[i]; \
      e0 = dot2u(wa##i.x, h.x, e0); e1 = dot2u(wa##i.y, h.y, e1); \
      e2 = dot2u(wa##i.z, h.z, e2); e3 = dot2u(wa##i.w, h.w, e3); }
      REP25(DOTE)
#undef DOTE
#define DOTP(i) { uint4 h = hc[25+i]; \
      e0 = dot2u(wb##i.x, h.x, e0); e1 = dot2u(wb##i.y, h.y, e1); \
      e2 = dot2u(wb##i.z, h.z, e2); e3 = dot2u(wb##i.w, h.w, e3); }
      REP7(DOTP)
#undef DOTP
      float eacc = (e0+e1)+(e2+e3);
      int q = tid - 400;
      if (q < 50){
        float mu = eacc;
        etas[(size_t)(s*50 + t)*50 + q] = mu;
        if (t == 0) klLocal += 0.5f*mu*mu/(1.f + 1e-6f);
        else { float d = mu - muPrev; klLocal += 0.5f*d*d*inv_dl; }
        muPrev = mu;
        ((_Float16*)hn)[200 + q] = (_Float16)mu;
      } else {
        float ls = eacc;
        if (t == 0) klLocal += 0.5f*(__expf(ls)/(1.f + 1e-6f) - 1.f - ls);
        else {
          ls = fminf(fmaxf(ls, -10.f), 10.f);
          klLocal += 0.5f*(__expf(ls)*inv_dl - 1.f + logdl - ls);
        }
      }
    }
    // no 3rd barrier: step t+1's writes are separated from step t's reads by B1/B2,
    // and concurrent regions (h dwords 0..99 vs eta dwords 100..124) are disjoint.
  }
  __syncthreads();
  blockReduceAdd(klLocal, red, W + OFF_SCAL + 2);
}

// ---------------- h1 = relu(hpre + b1 + eta_std @ W1E^T) -> bf16 ----------------
__global__ __launch_bounds__(256) void k_h1(
    const float* __restrict__ hpre, const float* __restrict__ b1, const float* __restrict__ w1e,
    const float* __restrict__ etas, const int* __restrict__ times, const int* __restrict__ srcs,
    ushort_t* __restrict__ h1B)
{
  int b = blockIdx.x, tid = threadIdx.x;
  __shared__ float et[50];
  int tb = times[b], sb = srcs[b];
  if (tid < 50) et[tid] = etas[(size_t)(sb*50 + tb)*50 + tid];
  __syncthreads();
  for (int j = tid; j < 800; j += 256){
    float acc = hpre[(size_t)b*800 + j] + b1[j];
    const float* wrow = w1e + (size_t)j*50;
    #pragma unroll
    for (int k = 0; k < 50; k++) acc += et[k]*wrow[k];
    h1B[(size_t)b*800 + j] = f2bf(fmaxf(acc, 0.f));
  }
}

// ---------------- theta head (h2pre + b2, relu folded; wcoef = theta/Z) ----------------
__global__ __launch_bounds__(256) void k_thfin(
    const float* __restrict__ h2g, const float* __restrict__ b2, const float* __restrict__ etas,
    const int* __restrict__ times, const int* __restrict__ srcs,
    const float* __restrict__ muW, const float* __restrict__ muB,
    const float* __restrict__ lsW, const float* __restrict__ lsB,
    const float* __restrict__ clsW, const float* __restrict__ clsB,
    const float* __restrict__ Zrow, float* __restrict__ wcoef, float* __restrict__ W)
{
  int b = blockIdx.x, tid = threadIdx.x;
  __shared__ float h2s[800], mu[50], lsv[50], et[50], th[50], lg[10], red[64], shm[2];
  for (int j = tid; j < 800; j += 256) h2s[j] = fmaxf(h2g[(size_t)b*800 + j] + b2[j], 0.f);
  int tb = times[b], sb = srcs[b];
  if (tid < 50) et[tid] = etas[(size_t)(sb*50 + tb)*50 + tid];
  __syncthreads();
  if (tid < 100){
    int q = (tid < 50) ? tid : tid - 50;
    const float* w = (tid < 50) ? (muW + (size_t)q*800) : (lsW + (size_t)q*800);
    float acc = (tid < 50) ? muB[q] : lsB[q];
    #pragma unroll 8
    for (int j = 0; j < 800; j++) acc += h2s[j]*w[j];
    if (tid < 50) mu[q] = acc;
    else lsv[q] = fminf(fmaxf(acc, -10.f), 10.f);
  }
  __syncthreads();
  if (tid == 0){ float m = -1e30f; for (int k = 0; k < 50; k++) m = fmaxf(m, mu[k]); shm[0] = m; }
  __syncthreads();
  if (tid < 50) th[tid] = __expf(mu[tid] - shm[0]);
  __syncthreads();
  if (tid == 0){ float z = 0.f; for (int k = 0; k < 50; k++) z += th[k]; shm[1] = z; }
  __syncthreads();
  if (tid < 64) red[tid] = 0.f;
  if (tid < 50){
    float t_ = th[tid]/shm[1]; th[tid] = t_;
    wcoef[(size_t)b*50 + tid] = t_/Zrow[tb*50 + tid];
    float d = mu[tid] - et[tid];
    red[tid] = 0.5f*((__expf(lsv[tid]) + d*d)/(1.f + 1e-6f) - 1.f - lsv[tid]);
  }
  __syncthreads();
  if (tid < 10){
    float a = clsB[tid];
    #pragma unroll
    for (int k = 0; k < 50; k++) a += th[k]*clsW[tid*50 + k];
    lg[tid] = a;
  }
  __syncthreads();
  if (tid == 0){
    float m = -1e30f; for (int i = 0; i < 10; i++) m = fmaxf(m, lg[i]);
    float z = 0.f; for (int i = 0; i < 10; i++) z += __expf(lg[i] - m);
    float lse = m + __logf(z);
    atomicAdd(W + OFF_SCAL + 4, lse - lg[sb]);
    float ssum = 0.f; for (int i = 0; i < 50; i++) ssum += red[i];
    atomicAdd(W + OFF_SCAL + 3, ssum);
  }
}

// ---------------- nll: E already exponentiated ----------------
__global__ __launch_bounds__(256) void k_nll(
    const _Float16* __restrict__ E, const float* __restrict__ wcoef,
    const float* __restrict__ bows, float* __restrict__ W)
{
  int t = blockIdx.x/10, vc = blockIdx.x%10;
  int v0 = vc*2000;
  int tid = threadIdx.x;
  const int* docCnt = (const int*)(W + OFF_DOCCNT);
  const int* docList = (const int*)(W + OFF_DOCLIST);
  __shared__ float wch[64*50];
  __shared__ int ids[64];
  __shared__ float red[256];
  int nd = docCnt[t];
  float acc = 0.f;
  for (int d0 = 0; d0 < nd; d0 += 64){
    int ndc = min(64, nd - d0);
    __syncthreads();
    for (int i = tid; i < ndc*50; i += 256){
      int d = i/50, k = i - d*50;
      int bb = docList[t*256 + d0 + d];
      if (k == 0) ids[d] = bb;
      wch[i] = wcoef[(size_t)bb*50 + k];
    }
    __syncthreads();
    for (int v = v0 + tid; v < v0 + 2000; v += 256){
      float e[50];
      #pragma unroll
      for (int k = 0; k < 50; k++)
        e[k] = (float)E[(size_t)(t*50 + k)*NVOC + v];
      for (int d = 0; d < ndc; d++){
        float s = 0.f;
        #pragma unroll
        for (int k = 0; k < 50; k++) s += wch[d*50 + k]*e[k];
        acc += bows[(size_t)ids[d]*NVOC + v]*__logf(s);
      }
    }
  }
  __syncthreads();
  blockReduceAdd(acc, red, W + OFF_SCAL + 0);
}

// ---------------- finalize ----------------
__global__ void k_final(const float* __restrict__ W, const int* __restrict__ ndocs, float* __restrict__ out)
{
  if (blockIdx.x == 0 && threadIdx.x == 0){
    float coeff = (float)ndocs[0] / 256.f;
    const float* scal = W + OFF_SCAL;
    float nll  = -scal[0]*coeff;
    float kla  = scal[1];
    float kle  = scal[2];
    float klth = scal[3]*coeff;
    float pred = scal[4]*coeff;
    out[0] = nll + kla + kle + klth + pred;
    out[1] = nll; out[2] = kla; out[3] = kle; out[4] = klth; out[5] = pred;
  }
}

extern "C" void kernel_launch(void* const* d_in, const int* in_sizes, int n_in,
                              void* d_out, int out_size, void* d_ws, size_t ws_size,
                              hipStream_t stream)
{
  (void)in_sizes; (void)n_in; (void)out_size; (void)ws_size;
  const float* bows  = (const float*)d_in[1];
  const float* nb    = (const float*)d_in[2];
  const int*   times = (const int*)d_in[3];
  const int*   srcs  = (const int*)d_in[4];
  const float* rnn   = (const float*)d_in[5];
  const int*   ndocs = (const int*)d_in[6];
  const float* muq   = (const float*)d_in[7];
  const float* lsq   = (const float*)d_in[8];
  const float* rho   = (const float*)d_in[9];
  const float* W1    = (const float*)d_in[10];
  const float* b1    = (const float*)d_in[11];
  const float* W2    = (const float*)d_in[12];
  const float* b2    = (const float*)d_in[13];
  const float* muthW = (const float*)d_in[14];
  const float* muthB = (const float*)d_in[15];
  const float* lsthW = (const float*)d_in[16];
  const float* lsthB = (const float*)d_in[17];
  const float* emapW = (const float*)d_in[18];
  const float* emapB = (const float*)d_in[19];
  const float* wih   = (const float*)d_in[20];
  const float* whh   = (const float*)d_in[21];
  const float* bih   = (const float*)d_in[22];
  const float* bhh   = (const float*)d_in[23];
  const float* muEW  = (const float*)d_in[24];
  const float* muEB  = (const float*)d_in[25];
  const float* lsEW  = (const float*)d_in[26];
  const float* lsEB  = (const float*)d_in[27];
  const float* clsW  = (const float*)d_in[28];
  const float* clsB  = (const float*)d_in[29];

  float* W = (float*)d_ws;
  ushort_t* alphaB = (ushort_t*)(W + OFF_ALPHAB);
  ushort_t* rhoB   = (ushort_t*)(W + OFF_RHOB);
  ushort_t* nbB    = (ushort_t*)(W + OFF_NBB);
  ushort_t* w1B    = (ushort_t*)(W + OFF_W1B);
  ushort_t* rnnB   = (ushort_t*)(W + OFF_RNNB);
  ushort_t* emwB   = (ushort_t*)(W + OFF_EMWB);
  ushort_t* wihB   = (ushort_t*)(W + OFF_WIHB);
  ushort_t* w2B    = (ushort_t*)(W + OFF_W2B);
  ushort_t* mapB   = (ushort_t*)(W + OFF_MAPB);
  ushort_t* h1B    = (ushort_t*)(W + OFF_H1B);
  _Float16* Ehalf  = (_Float16*)(W + OFF_LOGITH);

  hipMemsetAsync(d_ws, 0, MEMSET_BYTES, stream);

  // one launch: prep + all bf16 conversions + kl_alpha
  k_mega<<<24285, 256, 0, stream>>>(whh, muEW, lsEW, bih, bhh, wih, emapB, W1, times,
                                    muq, lsq, rho, nb, rnn, emapW, W2, W);

  // mapped = rnn @ eta_map_W^T  M=500 N=200 K=20000  (split-K atomic)
  mfma_nt<0><<<4*2*32, 256, 0, stream>>>(
      rnnB, 20000, emwB, 20000, W + OFF_MAPPED, nullptr, 200, nullptr,
      500, 200, 4, 32, 625);

  // hpre = nb @ W1[:, :V]^T  M=256 N=800 K=20000  (split-K atomic)
  mfma_nt<0><<<2*7*20, 256, 0, stream>>>(
      nbB, 20000, w1B, 20000, W + OFF_HPRE, nullptr, 800, nullptr,
      256, 800, 2, 20, 625);

  // E = exp(alphasT @ rho^T) -> f16 + row-sums Z   M=2500 N=20000 K=320
  // (overwrites w1B/rnnB/emwB region — must run after mapped & hpre gemms)
  mfma_nt<3><<<20*157, 256, 0, stream>>>(
      alphaB, 320, rhoB, 320, W + OFF_Z, Ehalf, 20000, nullptr,
      2500, 20000, 20, 1, 10);

  // mapped -> bf16 [512][224]
  k_conv<<<56, 256, 0, stream>>>(W + OFF_MAPPED, 200, 500, 200, mapB, 512, 224);

  // xw = mapped @ wih^T + bias2  M=500 N=800 K=224
  mfma_nt<2><<<4*7, 256, 0, stream>>>(
      mapB, 224, wihB, 224, W + OFF_XW, nullptr, 800, W + OFF_BIAS2,
      500, 800, 4, 1, 7);

  k_lstm<<<NSRC, 512, 0, stream>>>(W + OFF_XW, (const u32*)(W + OFF_WHH_H),
                                   (const uint4*)(W + OFF_ETAWH), muEB, lsEB,
                                   W + OFF_ETAS, W);

  k_h1<<<256, 256, 0, stream>>>(W + OFF_HPRE, b1, W + OFF_W1E, W + OFF_ETAS, times, srcs, h1B);

  // h2pre = h1 @ W2^T  M=256 N=800 K=800  (split-K atomic; b2+relu folded into k_thfin)
  mfma_nt<0><<<2*7*2, 256, 0, stream>>>(
      h1B, 800, w2B, 800, W + OFF_H2, nullptr, 800, nullptr,
      256, 800, 2, 2, 25);

  k_thfin<<<256, 256, 0, stream>>>(W + OFF_H2, b2, W + OFF_ETAS, times, srcs,
                                   muthW, muthB, lsthW, lsthB, clsW, clsB,
                                   W + OFF_Z, W + OFF_WCOEF, W);

  k_nll<<<500, 256, 0, stream>>>(Ehalf, W + OFF_WCOEF, bows, W);

  k_final<<<1, 64, 0, stream>>>(W, ndocs, (float*)d_out);
}